// Round 1
// baseline (7137.824 us; speedup 1.0000x reference)
//
#include <hip/hip_runtime.h>

// ---- problem constants ----
constexpr int EN   = 100000;  // edges
constexpr int NN   = 10000;   // nodes
constexpr int DEPTH = 6;
constexpr int NSEG = 100;

__device__ inline float wred_max(float v){
#pragma unroll
  for (int o = 32; o > 0; o >>= 1) v = fmaxf(v, __shfl_xor(v, o, 64));
  return v;
}
__device__ inline float wred_sum(float v){
#pragma unroll
  for (int o = 32; o > 0; o >>= 1) v += __shfl_xor(v, o, 64);
  return v;
}
__device__ inline float siluf(float x){ return x / (1.f + __expf(-x)); }

// ---- geometry + dst histogram ----
__global__ __launch_bounds__(256) void geom_k(const int* __restrict__ edges,
                                              const float* __restrict__ x,
                                              float* __restrict__ d_e,
                                              float* __restrict__ dirs,
                                              float* __restrict__ rbf_b,
                                              int* __restrict__ counts){
  int e = blockIdx.x * 256 + threadIdx.x;
  if (e >= EN) return;
  int dst = edges[2*e], src = edges[2*e+1];
  float dx = x[dst*3+0] - x[src*3+0];
  float dy = x[dst*3+1] - x[src*3+1];
  float dz = x[dst*3+2] - x[src*3+2];
  float dd = sqrtf(dx*dx + dy*dy + dz*dz + 1e-10f);
  d_e[e] = dd;
  float inv = 1.f / (dd + 1e-5f);
  dirs[3*e+0] = dx*inv; dirs[3*e+1] = dy*inv; dirs[3*e+2] = dz*inv;
  rbf_b[e] = __expf(-dd);
  atomicAdd(&counts[dst], 1);
}

// ---- exclusive scan of counts -> offsets (single block) ----
__global__ __launch_bounds__(256) void scan_k(const int* __restrict__ counts,
                                              int* __restrict__ offs){
  __shared__ int part[256];
  const int CH = (NN + 255) / 256;  // 40
  int t = threadIdx.x;
  int s = 0;
  for (int j = 0; j < CH; ++j){ int idx = t*CH + j; if (idx < NN) s += counts[idx]; }
  part[t] = s;
  __syncthreads();
  if (t == 0){
    int run = 0;
    for (int i = 0; i < 256; ++i){ int v = part[i]; part[i] = run; run += v; }
    offs[NN] = run;
  }
  __syncthreads();
  int run = part[t];
  for (int j = 0; j < CH; ++j){
    int idx = t*CH + j;
    if (idx < NN){ offs[idx] = run; run += counts[idx]; }
  }
}

// ---- CSR fill ----
__global__ __launch_bounds__(256) void fill_k(const int* __restrict__ edges,
                                              const int* __restrict__ offs,
                                              int* __restrict__ cursor,
                                              int* __restrict__ eid){
  int e = blockIdx.x * 256 + threadIdx.x;
  if (e >= EN) return;
  int dst = edges[2*e];
  int pos = offs[dst] + atomicAdd(&cursor[dst], 1);
  eid[pos] = e;
}

// ---- build edge input: ein[e][0:128]=concat(h[dst],h[src]), ein[e][178]=d ----
__global__ __launch_bounds__(256) void build_ein_k(const int* __restrict__ edges,
                                                   const float* __restrict__ h,
                                                   const float* __restrict__ d_e,
                                                   float* __restrict__ ein){
  int gid = blockIdx.x * 256 + threadIdx.x;
  int e = gid >> 7, j = gid & 127;
  if (e >= EN) return;
  int dst = edges[2*e], src = edges[2*e+1];
  float v = (j < 64) ? h[(size_t)dst*64 + j] : h[(size_t)src*64 + (j-64)];
  ein[(size_t)e*180 + j] = v;
  if (j == 0) ein[(size_t)e*180 + 178] = d_e[e];
}

// ---- generic tiled GEMM: out = EPI(A @ W + bias) ----
// EPI: 0=none 1=silu 2=tanh(no bias) 3=rbf-scale 4=resid+silu
// AMODE: 0 = A[m][k] (lda), 1 = A is he[m][64], value = he[m][k>>2]*att[m][k&3]
template<int EPI, int AMODE>
__global__ __launch_bounds__(256) void gemm_k(const float* __restrict__ A, int lda,
                                              const float* __restrict__ W, int ldw,
                                              const float* __restrict__ bias,
                                              float* __restrict__ out, int ldo, int ocol,
                                              int M, int N, int K,
                                              const float* __restrict__ e0,
                                              const float* __restrict__ e1,
                                              const float* __restrict__ e2,
                                              const float* __restrict__ attp){
  __shared__ float w_s[128*64];
  const int tid  = threadIdx.x;
  const int nl   = tid & 63;
  const int rg   = tid >> 6;
  const int col0 = blockIdx.y * 64;
  const int m0   = blockIdx.x * 16 + rg * 4;
  float acc[4] = {0.f, 0.f, 0.f, 0.f};
  const float* ar[4];
  float at[4][4];
#pragma unroll
  for (int r = 0; r < 4; ++r){
    int mr = min(m0 + r, M - 1);
    if (AMODE == 0){
      ar[r] = A + (size_t)mr * lda;
    } else {
      ar[r] = A + (size_t)mr * 64;
#pragma unroll
      for (int j = 0; j < 4; ++j) at[r][j] = attp[(size_t)mr*4 + j];
    }
  }
  for (int kc = 0; kc < K; kc += 128){
    int kn = min(128, K - kc);
    for (int idx = tid; idx < 128*64; idx += 256){
      int kk = idx >> 6, nn = idx & 63;
      int gn = col0 + nn;
      w_s[idx] = (kk < kn && gn < N) ? W[(size_t)(kc+kk)*ldw + gn] : 0.f;
    }
    __syncthreads();
    if (AMODE == 0){
      for (int k = 0; k < kn; ++k){
        float wv = w_s[k*64 + nl];
#pragma unroll
        for (int r = 0; r < 4; ++r) acc[r] = fmaf(ar[r][kc + k], wv, acc[r]);
      }
    } else {
      for (int k = 0; k < kn; k += 4){
        int q = (kc + k) >> 2;
        float hv[4];
#pragma unroll
        for (int r = 0; r < 4; ++r) hv[r] = ar[r][q];
#pragma unroll
        for (int j = 0; j < 4; ++j){
          float wv = w_s[(k+j)*64 + nl];
#pragma unroll
          for (int r = 0; r < 4; ++r) acc[r] = fmaf(hv[r] * at[r][j], wv, acc[r]);
        }
      }
    }
    __syncthreads();
  }
  int n = col0 + nl;
  if (n >= N) return;
  float b = bias ? bias[n] : 0.f;
#pragma unroll
  for (int r = 0; r < 4; ++r){
    int m = m0 + r;
    if (m >= M) break;
    float a = acc[r], v;
    if (EPI == 0)      v = a + b;
    else if (EPI == 1) v = siluf(a + b);
    else if (EPI == 2) v = tanhf(a);
    else if (EPI == 3){ float rb = e0[m]; float df = rb - e1[n]; v = __expf(-e2[n]*df*df) * (a + b); }
    else               v = e0[(size_t)m*64 + n] + siluf(a + b);
    out[(size_t)m*ldo + ocol + n] = v;
  }
}

// ---- sem head logits + celu(alpha=2) ----
__global__ __launch_bounds__(256) void sem_k(const float* __restrict__ he,
                                             const float* __restrict__ sw,
                                             const float* __restrict__ sb,
                                             float* __restrict__ logit){
  __shared__ float tile[64*65];
  int e0 = blockIdx.x * 64;
  for (int idx = threadIdx.x; idx < 64*64; idx += 256){
    int r = idx >> 6, cc = idx & 63;
    int e = e0 + r;
    tile[r*65 + cc] = (e < EN) ? he[(size_t)e*64 + cc] : 0.f;
  }
  __syncthreads();
  int er = threadIdx.x >> 2, hd = threadIdx.x & 3;
  int e = e0 + er;
  float acc = sb[hd];
#pragma unroll 8
  for (int k = 0; k < 64; ++k) acc = fmaf(tile[er*65 + k], sw[k*4 + hd], acc);
  float v = acc > 0.f ? acc : 2.f*(__expf(0.5f*acc) - 1.f);
  if (e < EN) logit[(size_t)e*4 + hd] = v;
}

// ---- per-node attention: att = norm(softmax(-d) * softmax(celu_logits)) ----
__global__ __launch_bounds__(256) void att_k(const int* __restrict__ offs,
                                             const int* __restrict__ eid,
                                             const float* __restrict__ d_e,
                                             const float* __restrict__ logit,
                                             float* __restrict__ att){
  int lane = threadIdx.x & 63;
  int node = (blockIdx.x * 256 + threadIdx.x) >> 6;
  if (node >= NN) return;
  int s0 = offs[node];
  int cnt = offs[node+1] - s0;
  if (cnt <= 0) return;
  const float NEG = -1e30f;
  float me = NEG, ms0 = NEG, ms1 = NEG, ms2 = NEG, ms3 = NEG;
  for (int base = 0; base < cnt; base += 64){
    int j = base + lane;
    if (j < cnt){
      int e = eid[s0 + j];
      float dd = d_e[e];
      me = fmaxf(me, -dd);
      float4 lg = *reinterpret_cast<const float4*>(logit + 4*(size_t)e);
      ms0 = fmaxf(ms0, lg.x); ms1 = fmaxf(ms1, lg.y);
      ms2 = fmaxf(ms2, lg.z); ms3 = fmaxf(ms3, lg.w);
    }
  }
  me = wred_max(me); ms0 = wred_max(ms0); ms1 = wred_max(ms1);
  ms2 = wred_max(ms2); ms3 = wred_max(ms3);
  float se = 0.f, ss0 = 0.f, ss1 = 0.f, ss2 = 0.f, ss3 = 0.f;
  for (int base = 0; base < cnt; base += 64){
    int j = base + lane;
    if (j < cnt){
      int e = eid[s0 + j];
      float dd = d_e[e];
      float4 lg = *reinterpret_cast<const float4*>(logit + 4*(size_t)e);
      se  += __expf(-dd - me);
      ss0 += __expf(lg.x - ms0); ss1 += __expf(lg.y - ms1);
      ss2 += __expf(lg.z - ms2); ss3 += __expf(lg.w - ms3);
    }
  }
  se = wred_sum(se); ss0 = wred_sum(ss0); ss1 = wred_sum(ss1);
  ss2 = wred_sum(ss2); ss3 = wred_sum(ss3);
  float ise = 1.f/se, is0 = 1.f/ss0, is1 = 1.f/ss1, is2 = 1.f/ss2, is3 = 1.f/ss3;
  float z0 = 0.f, z1 = 0.f, z2 = 0.f, z3 = 0.f;
  for (int base = 0; base < cnt; base += 64){
    int j = base + lane;
    if (j < cnt){
      int e = eid[s0 + j];
      float dd = d_e[e];
      float4 lg = *reinterpret_cast<const float4*>(logit + 4*(size_t)e);
      float ae = __expf(-dd - me) * ise;
      z0 += ae * __expf(lg.x - ms0) * is0;
      z1 += ae * __expf(lg.y - ms1) * is1;
      z2 += ae * __expf(lg.z - ms2) * is2;
      z3 += ae * __expf(lg.w - ms3) * is3;
    }
  }
  z0 = wred_sum(z0); z1 = wred_sum(z1); z2 = wred_sum(z2); z3 = wred_sum(z3);
  float iz0 = 1.f/z0, iz1 = 1.f/z1, iz2 = 1.f/z2, iz3 = 1.f/z3;
  for (int base = 0; base < cnt; base += 64){
    int j = base + lane;
    if (j < cnt){
      int e = eid[s0 + j];
      float dd = d_e[e];
      float4 lg = *reinterpret_cast<const float4*>(logit + 4*(size_t)e);
      float ae = __expf(-dd - me) * ise;
      float4 o;
      o.x = ae * __expf(lg.x - ms0) * is0 * iz0;
      o.y = ae * __expf(lg.y - ms1) * is1 * iz1;
      o.z = ae * __expf(lg.z - ms2) * is2 * iz2;
      o.w = ae * __expf(lg.w - ms3) * is3 * iz3;
      *reinterpret_cast<float4*>(att + 4*(size_t)e) = o;
    }
  }
}

// ---- copy h into node_in[:,0:64] ----
__global__ __launch_bounds__(256) void copyh_k(const float* __restrict__ h,
                                               float* __restrict__ node_in){
  int gid = blockIdx.x * 256 + threadIdx.x;
  if (gid >= NN*64) return;
  int n = gid >> 6, ch = gid & 63;
  node_in[(size_t)n*384 + ch] = h[gid];
}

// ---- per-node aggregate: cnorm = |sum coef*dirs|^2, h_agg = sum he*att ----
__global__ __launch_bounds__(256) void agg_k(const int* __restrict__ offs,
                                             const int* __restrict__ eid,
                                             const float* __restrict__ coef,
                                             const float* __restrict__ he,
                                             const float* __restrict__ att,
                                             const float* __restrict__ dirs,
                                             float* __restrict__ cnorm,
                                             float* __restrict__ node_in){
  int node = blockIdx.x;
  int c = threadIdx.x;
  int s0 = offs[node], cnt = offs[node+1] - s0;
  int q = c >> 2, hd = c & 3;
  float cs0 = 0.f, cs1 = 0.f, cs2 = 0.f, ha = 0.f;
  for (int j = 0; j < cnt; ++j){
    int e = eid[s0 + j];
    float co = coef[(size_t)e*256 + c];
    float hv = he[(size_t)e*64 + q] * att[(size_t)e*4 + hd];
    float d0 = dirs[3*(size_t)e], d1 = dirs[3*(size_t)e+1], d2 = dirs[3*(size_t)e+2];
    cs0 = fmaf(co, d0, cs0); cs1 = fmaf(co, d1, cs1); cs2 = fmaf(co, d2, cs2);
    ha += hv;
  }
  cnorm[(size_t)node*256 + c] = cs0*cs0 + cs1*cs1 + cs2*cs2;
  node_in[(size_t)node*384 + 64 + c] = ha;
}

// ---- graph pooling ----
__global__ __launch_bounds__(256) void segy_k(const float* __restrict__ hf,
                                              const int* __restrict__ seg,
                                              float* __restrict__ y){
  int gid = blockIdx.x * 256 + threadIdx.x;
  if (gid >= NN*64) return;
  int n = gid >> 6, ch = gid & 63;
  atomicAdd(&y[seg[n]*64 + ch], hf[gid]);
}

// ---- final head ----
__global__ void headf_k(const float* __restrict__ t2,
                        const float* __restrict__ w2,
                        const float* __restrict__ b2,
                        float* __restrict__ out){
  int s = threadIdx.x;
  if (s >= NSEG) return;
  float acc = b2[0];
  for (int k = 0; k < 64; ++k) acc = fmaf(t2[s*64 + k], w2[k], acc);
  out[s] = acc;
}

extern "C" void kernel_launch(void* const* d_in, const int* in_sizes, int n_in,
                              void* d_out, int out_size, void* d_ws, size_t ws_size,
                              hipStream_t stream) {
  (void)in_sizes; (void)n_in; (void)out_size; (void)ws_size;
  const float* in_i       = (const float*)d_in[0];
  const float* in_x       = (const float*)d_in[1];
  const float* emb_in_w   = (const float*)d_in[2];
  const float* emb_in_b   = (const float*)d_in[3];
  const float* edge_in_w  = (const float*)d_in[4];
  const float* edge_in_b  = (const float*)d_in[5];
  const float* rbf_means  = (const float*)d_in[6];
  const float* rbf_betas  = (const float*)d_in[7];
  const float* edge_o_w1  = (const float*)d_in[8];
  const float* edge_o_b1  = (const float*)d_in[9];
  const float* edge_o_w2  = (const float*)d_in[10];
  const float* edge_o_b2  = (const float*)d_in[11];
  const float* sem_w      = (const float*)d_in[12];
  const float* sem_b      = (const float*)d_in[13];
  const float* xmix_w     = (const float*)d_in[14];
  const float* pn_w1      = (const float*)d_in[15];
  const float* pn_b1      = (const float*)d_in[16];
  const float* pn_w2      = (const float*)d_in[17];
  const float* pn_b2      = (const float*)d_in[18];
  const float* node_w1    = (const float*)d_in[19];
  const float* node_b1    = (const float*)d_in[20];
  const float* node_w2    = (const float*)d_in[21];
  const float* node_b2    = (const float*)d_in[22];
  const float* emb_o_w1   = (const float*)d_in[23];
  const float* emb_o_b1   = (const float*)d_in[24];
  const float* emb_o_w2   = (const float*)d_in[25];
  const float* emb_o_b2   = (const float*)d_in[26];
  const float* head_w1    = (const float*)d_in[27];
  const float* head_b1    = (const float*)d_in[28];
  const float* head_w2    = (const float*)d_in[29];
  const float* head_b2    = (const float*)d_in[30];
  const int*   edges      = (const int*)d_in[31];
  const int*   segs       = (const int*)d_in[32];
  float* out = (float*)d_out;

  // workspace carve-up (256B aligned)
  char* base = (char*)d_ws;
  size_t off = 0;
  auto alloc = [&](size_t bytes) -> void* {
    void* p = base + off;
    off += (bytes + 255) & ~(size_t)255;
    return p;
  };
  float* d_e    = (float*)alloc((size_t)EN*4);
  float* dirs   = (float*)alloc((size_t)EN*3*4);
  float* rbf_b  = (float*)alloc((size_t)EN*4);
  float* hA     = (float*)alloc((size_t)NN*64*4);
  float* hB     = (float*)alloc((size_t)NN*64*4);
  float* bufA   = (float*)alloc((size_t)EN*256*4);  // ein (E x 180) | coef (E x 256)
  float* he     = (float*)alloc((size_t)EN*64*4);
  float* t_edge = (float*)alloc((size_t)EN*64*4);
  float* logit  = (float*)alloc((size_t)EN*4*4);
  float* att    = (float*)alloc((size_t)EN*4*4);
  float* cnorm  = (float*)alloc((size_t)NN*256*4);
  float* node_in= (float*)alloc((size_t)NN*384*4);
  float* pn_t   = (float*)alloc((size_t)NN*64*4);
  float* t_node = (float*)alloc((size_t)NN*64*4);
  float* y      = (float*)alloc((size_t)NSEG*64*4);
  float* t2     = (float*)alloc((size_t)NSEG*64*4);
  int* counts   = (int*)alloc((size_t)NN*4);
  int* cursor   = (int*)alloc((size_t)NN*4);
  int* offs     = (int*)alloc((size_t)(NN+1)*4);
  int* eid      = (int*)alloc((size_t)EN*4);
  float* ein = bufA;   // E x 180
  float* coef = bufA;  // E x 256 (after ein is dead)

  hipMemsetAsync(counts, 0, (size_t)NN*4, stream);
  hipMemsetAsync(cursor, 0, (size_t)NN*4, stream);
  hipMemsetAsync(y, 0, (size_t)NSEG*64*4, stream);

  geom_k<<<(EN+255)/256, 256, 0, stream>>>(edges, in_x, d_e, dirs, rbf_b, counts);
  scan_k<<<1, 256, 0, stream>>>(counts, offs);
  fill_k<<<(EN+255)/256, 256, 0, stream>>>(edges, offs, cursor, eid);

  // h = i @ emb_in_w + b
  gemm_k<0,0><<<dim3((NN+15)/16, 1), 256, 0, stream>>>(
      in_i, 16, emb_in_w, 64, emb_in_b, hA, 64, 0, NN, 64, 16,
      nullptr, nullptr, nullptr, nullptr);

  float* hcur = hA;
  float* hnext = hB;
  for (int l = 0; l < DEPTH; ++l){
    const float* Win  = edge_in_w + (size_t)l*128*50;
    const float* bin  = edge_in_b + (size_t)l*50;
    const float* mean = rbf_means + (size_t)l*50;
    const float* beta = rbf_betas + (size_t)l*50;
    const float* W1   = edge_o_w1 + (size_t)l*179*64;
    const float* b1   = edge_o_b1 + (size_t)l*64;
    const float* W2   = edge_o_w2 + (size_t)l*64*64;
    const float* b2   = edge_o_b2 + (size_t)l*64;
    const float* sw   = sem_w + (size_t)l*64*4;
    const float* sb   = sem_b + (size_t)l*4;
    const float* xw   = xmix_w + (size_t)l*256*256;
    const float* pw1  = pn_w1 + (size_t)l*256*64;
    const float* pb1  = pn_b1 + (size_t)l*64;
    const float* pw2  = pn_w2 + (size_t)l*64*64;
    const float* pb2  = pn_b2 + (size_t)l*64;
    const float* nw1  = node_w1 + (size_t)l*384*64;
    const float* nb1  = node_b1 + (size_t)l*64;
    const float* nw2  = node_w2 + (size_t)l*64*64;
    const float* nb2  = node_b2 + (size_t)l*64;

    build_ein_k<<<(EN*128)/256, 256, 0, stream>>>(edges, hcur, d_e, ein);
    // hm -> rbf*hm written into ein[:,128:178]
    gemm_k<3,0><<<dim3(EN/16, 1), 256, 0, stream>>>(
        ein, 180, Win, 50, bin, ein, 180, 128, EN, 50, 128,
        rbf_b, mean, beta, nullptr);
    // t = silu(ein @ W1 + b1)   (K=179 covers [hc, rbf*hm, d])
    gemm_k<1,0><<<dim3(EN/16, 1), 256, 0, stream>>>(
        ein, 180, W1, 64, b1, t_edge, 64, 0, EN, 64, 179,
        nullptr, nullptr, nullptr, nullptr);
    // he = t @ W2 + b2
    gemm_k<0,0><<<dim3(EN/16, 1), 256, 0, stream>>>(
        t_edge, 64, W2, 64, b2, he, 64, 0, EN, 64, 64,
        nullptr, nullptr, nullptr, nullptr);
    sem_k<<<(EN+63)/64, 256, 0, stream>>>(he, sw, sb, logit);
    att_k<<<(NN+3)/4, 256, 0, stream>>>(offs, eid, d_e, logit, att);
    // coef = tanh(hea @ xmix), hea computed on the fly from he,att
    gemm_k<2,1><<<dim3(EN/16, 4), 256, 0, stream>>>(
        he, 64, xw, 256, nullptr, coef, 256, 0, EN, 256, 256,
        nullptr, nullptr, nullptr, att);
    copyh_k<<<(NN*64)/256, 256, 0, stream>>>(hcur, node_in);
    agg_k<<<NN, 256, 0, stream>>>(offs, eid, coef, he, att, dirs, cnorm, node_in);
    // h_comb = silu(silu(cnorm@pn_w1+b1)@pn_w2+b2) -> node_in[:,320:384]
    gemm_k<1,0><<<dim3(NN/16, 1), 256, 0, stream>>>(
        cnorm, 256, pw1, 64, pb1, pn_t, 64, 0, NN, 64, 256,
        nullptr, nullptr, nullptr, nullptr);
    gemm_k<1,0><<<dim3(NN/16, 1), 256, 0, stream>>>(
        pn_t, 64, pw2, 64, pb2, node_in, 384, 320, NN, 64, 64,
        nullptr, nullptr, nullptr, nullptr);
    // node update
    gemm_k<1,0><<<dim3(NN/16, 1), 256, 0, stream>>>(
        node_in, 384, nw1, 64, nb1, t_node, 64, 0, NN, 64, 384,
        nullptr, nullptr, nullptr, nullptr);
    gemm_k<4,0><<<dim3(NN/16, 1), 256, 0, stream>>>(
        t_node, 64, nw2, 64, nb2, hnext, 64, 0, NN, 64, 64,
        hcur, nullptr, nullptr, nullptr);
    float* tmp = hcur; hcur = hnext; hnext = tmp;
  }

  // output head
  gemm_k<1,0><<<dim3(NN/16, 1), 256, 0, stream>>>(
      hcur, 64, emb_o_w1, 64, emb_o_b1, t_node, 64, 0, NN, 64, 64,
      nullptr, nullptr, nullptr, nullptr);
  gemm_k<0,0><<<dim3(NN/16, 1), 256, 0, stream>>>(
      t_node, 64, emb_o_w2, 64, emb_o_b2, hnext, 64, 0, NN, 64, 64,
      nullptr, nullptr, nullptr, nullptr);
  segy_k<<<(NN*64)/256, 256, 0, stream>>>(hnext, segs, y);
  gemm_k<1,0><<<dim3((NSEG+15)/16, 1), 256, 0, stream>>>(
      y, 64, head_w1, 64, head_b1, t2, 64, 0, NSEG, 64, 64,
      nullptr, nullptr, nullptr, nullptr);
  headf_k<<<1, 128, 0, stream>>>(t2, head_w2, head_b2, out);
}

// Round 2
// 4170.115 us; speedup vs baseline: 1.7117x; 1.7117x over previous
//
#include <hip/hip_runtime.h>
#include <hip/hip_bf16.h>

// ---- problem constants ----
constexpr int EN   = 100000;  // edges
constexpr int NN   = 10000;   // nodes
constexpr int DEPTH = 6;
constexpr int NSEG = 100;

typedef unsigned short u16;
typedef __bf16 bf16x8 __attribute__((ext_vector_type(8)));
typedef float  f32x4  __attribute__((ext_vector_type(4)));

__device__ inline float wred_max(float v){
#pragma unroll
  for (int o = 32; o > 0; o >>= 1) v = fmaxf(v, __shfl_xor(v, o, 64));
  return v;
}
__device__ inline float wred_sum(float v){
#pragma unroll
  for (int o = 32; o > 0; o >>= 1) v += __shfl_xor(v, o, 64);
  return v;
}
__device__ inline float siluf(float x){ return x / (1.f + __expf(-x)); }
__device__ inline u16 f2bf(float x){
  __hip_bfloat16 h = __float2bfloat16(x);
  return *reinterpret_cast<u16*>(&h);
}
__device__ inline float bf2f(u16 u){
  union { float f; unsigned int ui; } v; v.ui = ((unsigned int)u) << 16; return v.f;
}

// ---- geometry + dst histogram ----
__global__ __launch_bounds__(256) void geom_k(const int* __restrict__ edges,
                                              const float* __restrict__ x,
                                              float* __restrict__ d_e,
                                              float* __restrict__ dirs,
                                              float* __restrict__ rbf_b,
                                              int* __restrict__ counts){
  int e = blockIdx.x * 256 + threadIdx.x;
  if (e >= EN) return;
  int dst = edges[2*e], src = edges[2*e+1];
  float dx = x[dst*3+0] - x[src*3+0];
  float dy = x[dst*3+1] - x[src*3+1];
  float dz = x[dst*3+2] - x[src*3+2];
  float dd = sqrtf(dx*dx + dy*dy + dz*dz + 1e-10f);
  d_e[e] = dd;
  float inv = 1.f / (dd + 1e-5f);
  dirs[3*e+0] = dx*inv; dirs[3*e+1] = dy*inv; dirs[3*e+2] = dz*inv;
  rbf_b[e] = __expf(-dd);
  atomicAdd(&counts[dst], 1);
}

// ---- exclusive scan of counts -> offsets (single block) ----
__global__ __launch_bounds__(256) void scan_k(const int* __restrict__ counts,
                                              int* __restrict__ offs){
  __shared__ int part[256];
  const int CH = (NN + 255) / 256;  // 40
  int t = threadIdx.x;
  int s = 0;
  for (int j = 0; j < CH; ++j){ int idx = t*CH + j; if (idx < NN) s += counts[idx]; }
  part[t] = s;
  __syncthreads();
  if (t == 0){
    int run = 0;
    for (int i = 0; i < 256; ++i){ int v = part[i]; part[i] = run; run += v; }
    offs[NN] = run;
  }
  __syncthreads();
  int run = part[t];
  for (int j = 0; j < CH; ++j){
    int idx = t*CH + j;
    if (idx < NN){ offs[idx] = run; run += counts[idx]; }
  }
}

// ---- CSR fill ----
__global__ __launch_bounds__(256) void fill_k(const int* __restrict__ edges,
                                              const int* __restrict__ offs,
                                              int* __restrict__ cursor,
                                              int* __restrict__ eid){
  int e = blockIdx.x * 256 + threadIdx.x;
  if (e >= EN) return;
  int dst = edges[2*e];
  int pos = offs[dst] + atomicAdd(&cursor[dst], 1);
  eid[pos] = e;
}

// ---- build edge input: ein[e][0:128]=concat(h[dst],h[src]), ein[e][178]=d ----
__global__ __launch_bounds__(256) void build_ein_k(const int* __restrict__ edges,
                                                   const float* __restrict__ h,
                                                   const float* __restrict__ d_e,
                                                   float* __restrict__ ein){
  int gid = blockIdx.x * 256 + threadIdx.x;
  int e = gid >> 7, j = gid & 127;
  if (e >= EN) return;
  int dst = edges[2*e], src = edges[2*e+1];
  float v = (j < 64) ? h[(size_t)dst*64 + j] : h[(size_t)src*64 + (j-64)];
  ein[(size_t)e*180 + j] = v;
  if (j == 0) ein[(size_t)e*180 + 178] = d_e[e];
}

// ---- generic tiled fp32 GEMM: out = EPI(A @ W + bias) ----
// EPI: 0=none 1=silu 2=tanh(no bias) 3=rbf-scale 4=resid+silu
template<int EPI>
__global__ __launch_bounds__(256) void gemm_k(const float* __restrict__ A, int lda,
                                              const float* __restrict__ W, int ldw,
                                              const float* __restrict__ bias,
                                              float* __restrict__ out, int ldo, int ocol,
                                              int M, int N, int K,
                                              const float* __restrict__ e0,
                                              const float* __restrict__ e1,
                                              const float* __restrict__ e2){
  __shared__ float w_s[128*64];
  const int tid  = threadIdx.x;
  const int nl   = tid & 63;
  const int rg   = tid >> 6;
  const int col0 = blockIdx.y * 64;
  const int m0   = blockIdx.x * 16 + rg * 4;
  float acc[4] = {0.f, 0.f, 0.f, 0.f};
  const float* ar[4];
#pragma unroll
  for (int r = 0; r < 4; ++r){
    int mr = min(m0 + r, M - 1);
    ar[r] = A + (size_t)mr * lda;
  }
  for (int kc = 0; kc < K; kc += 128){
    int kn = min(128, K - kc);
    for (int idx = tid; idx < 128*64; idx += 256){
      int kk = idx >> 6, nn = idx & 63;
      int gn = col0 + nn;
      w_s[idx] = (kk < kn && gn < N) ? W[(size_t)(kc+kk)*ldw + gn] : 0.f;
    }
    __syncthreads();
    for (int k = 0; k < kn; ++k){
      float wv = w_s[k*64 + nl];
#pragma unroll
      for (int r = 0; r < 4; ++r) acc[r] = fmaf(ar[r][kc + k], wv, acc[r]);
    }
    __syncthreads();
  }
  int n = col0 + nl;
  if (n >= N) return;
  float b = bias ? bias[n] : 0.f;
#pragma unroll
  for (int r = 0; r < 4; ++r){
    int m = m0 + r;
    if (m >= M) break;
    float a = acc[r], v;
    if (EPI == 0)      v = a + b;
    else if (EPI == 1) v = siluf(a + b);
    else if (EPI == 2) v = tanhf(a);
    else if (EPI == 3){ float rb = e0[m]; float df = rb - e1[n]; v = __expf(-e2[n]*df*df) * (a + b); }
    else               v = e0[(size_t)m*64 + n] + siluf(a + b);
    out[(size_t)m*ldo + ocol + n] = v;
  }
}

// ---- convert+transpose xmix weights to bf16: Wt[l][n][k] = bf16(xmix[l][k][n]) ----
__global__ __launch_bounds__(256) void convx_k(const float* __restrict__ xmix,
                                               u16* __restrict__ wt){
  int n = blockIdx.x;          // 0..255
  int l = blockIdx.y;          // 0..5
  int k = threadIdx.x;         // 0..255
  wt[(size_t)l*65536 + n*256 + k] = f2bf(xmix[(size_t)l*65536 + (size_t)k*256 + n]);
}

// ---- build hea (bf16): hea[e][q*4+hd] = he[e][q]*att[e][hd] ----
__global__ __launch_bounds__(256) void hea_k(const float* __restrict__ he,
                                             const float* __restrict__ att,
                                             u16* __restrict__ hea){
  int gid = blockIdx.x * 256 + threadIdx.x;
  if (gid >= EN*64) return;
  int e = gid >> 6, q = gid & 63;
  float hv = he[(size_t)e*64 + q];
  float4 a = *reinterpret_cast<const float4*>(att + (size_t)e*4);
  union { u16 h[4]; ushort4 u; } pk;
  pk.h[0] = f2bf(hv * a.x);
  pk.h[1] = f2bf(hv * a.y);
  pk.h[2] = f2bf(hv * a.z);
  pk.h[3] = f2bf(hv * a.w);
  *reinterpret_cast<ushort4*>(hea + (size_t)e*256 + q*4) = pk.u;
}

// ---- bf16 MFMA GEMM with tanh epilogue: coef = tanh(hea @ xmix) ----
// A: M x lda bf16 row-major; Wt: (Ntiles*64) x ldw bf16 row-major (W transposed);
// out: M x ldo bf16. Tile 64x64, BK=32, 4 waves.
__global__ __launch_bounds__(256) void bgemm_tanh_k(const u16* __restrict__ A, int lda,
                                                    const u16* __restrict__ Wt, int ldw,
                                                    u16* __restrict__ out, int ldo,
                                                    int M, int K){
  __shared__ u16 A_s[64*32];
  __shared__ u16 B_s[64*32];
  const int tid  = threadIdx.x;
  const int lane = tid & 63;
  const int wave = tid >> 6;
  const int m0   = blockIdx.x * 64;
  const int n0   = blockIdx.y * 64;
  const int l15  = lane & 15;
  const int kq   = (lane >> 4) * 8;   // 0,8,16,24

  // staging coords: each thread moves 8 bf16 (16B) per buffer per K-step
  const int srow = tid >> 2;          // 0..63
  const int sk   = (tid & 3) * 8;     // 0,8,16,24
  const int arow = min(m0 + srow, M - 1);
  const size_t a_base = (size_t)arow * lda + sk;
  const size_t b_base = (size_t)(n0 + srow) * ldw + sk;

  f32x4 acc[4];
#pragma unroll
  for (int c = 0; c < 4; ++c) acc[c] = (f32x4){0.f, 0.f, 0.f, 0.f};

  for (int kc = 0; kc < K; kc += 32){
    *reinterpret_cast<uint4*>(A_s + srow*32 + sk) =
        *reinterpret_cast<const uint4*>(A + a_base + kc);
    *reinterpret_cast<uint4*>(B_s + srow*32 + sk) =
        *reinterpret_cast<const uint4*>(Wt + b_base + kc);
    __syncthreads();
    bf16x8 af = *reinterpret_cast<const bf16x8*>(A_s + (wave*16 + l15)*32 + kq);
#pragma unroll
    for (int c = 0; c < 4; ++c){
      bf16x8 bf = *reinterpret_cast<const bf16x8*>(B_s + (c*16 + l15)*32 + kq);
      acc[c] = __builtin_amdgcn_mfma_f32_16x16x32_bf16(af, bf, acc[c], 0, 0, 0);
    }
    __syncthreads();
  }

  // C/D: col = lane&15, row = (lane>>4)*4 + r
  const int rbase = m0 + wave*16 + (lane >> 4)*4;
#pragma unroll
  for (int c = 0; c < 4; ++c){
    int n = n0 + c*16 + l15;
#pragma unroll
    for (int r = 0; r < 4; ++r){
      int m = rbase + r;
      if (m < M) out[(size_t)m*ldo + n] = f2bf(tanhf(acc[c][r]));
    }
  }
}

// ---- sem head logits + celu(alpha=2) ----
__global__ __launch_bounds__(256) void sem_k(const float* __restrict__ he,
                                             const float* __restrict__ sw,
                                             const float* __restrict__ sb,
                                             float* __restrict__ logit){
  __shared__ float tile[64*65];
  int e0 = blockIdx.x * 64;
  for (int idx = threadIdx.x; idx < 64*64; idx += 256){
    int r = idx >> 6, cc = idx & 63;
    int e = e0 + r;
    tile[r*65 + cc] = (e < EN) ? he[(size_t)e*64 + cc] : 0.f;
  }
  __syncthreads();
  int er = threadIdx.x >> 2, hd = threadIdx.x & 3;
  int e = e0 + er;
  float acc = sb[hd];
#pragma unroll 8
  for (int k = 0; k < 64; ++k) acc = fmaf(tile[er*65 + k], sw[k*4 + hd], acc);
  float v = acc > 0.f ? acc : 2.f*(__expf(0.5f*acc) - 1.f);
  if (e < EN) logit[(size_t)e*4 + hd] = v;
}

// ---- per-node attention: att = norm(softmax(-d) * softmax(celu_logits)) ----
__global__ __launch_bounds__(256) void att_k(const int* __restrict__ offs,
                                             const int* __restrict__ eid,
                                             const float* __restrict__ d_e,
                                             const float* __restrict__ logit,
                                             float* __restrict__ att){
  int lane = threadIdx.x & 63;
  int node = (blockIdx.x * 256 + threadIdx.x) >> 6;
  if (node >= NN) return;
  int s0 = offs[node];
  int cnt = offs[node+1] - s0;
  if (cnt <= 0) return;
  const float NEG = -1e30f;
  float me = NEG, ms0 = NEG, ms1 = NEG, ms2 = NEG, ms3 = NEG;
  for (int base = 0; base < cnt; base += 64){
    int j = base + lane;
    if (j < cnt){
      int e = eid[s0 + j];
      float dd = d_e[e];
      me = fmaxf(me, -dd);
      float4 lg = *reinterpret_cast<const float4*>(logit + 4*(size_t)e);
      ms0 = fmaxf(ms0, lg.x); ms1 = fmaxf(ms1, lg.y);
      ms2 = fmaxf(ms2, lg.z); ms3 = fmaxf(ms3, lg.w);
    }
  }
  me = wred_max(me); ms0 = wred_max(ms0); ms1 = wred_max(ms1);
  ms2 = wred_max(ms2); ms3 = wred_max(ms3);
  float se = 0.f, ss0 = 0.f, ss1 = 0.f, ss2 = 0.f, ss3 = 0.f;
  for (int base = 0; base < cnt; base += 64){
    int j = base + lane;
    if (j < cnt){
      int e = eid[s0 + j];
      float dd = d_e[e];
      float4 lg = *reinterpret_cast<const float4*>(logit + 4*(size_t)e);
      se  += __expf(-dd - me);
      ss0 += __expf(lg.x - ms0); ss1 += __expf(lg.y - ms1);
      ss2 += __expf(lg.z - ms2); ss3 += __expf(lg.w - ms3);
    }
  }
  se = wred_sum(se); ss0 = wred_sum(ss0); ss1 = wred_sum(ss1);
  ss2 = wred_sum(ss2); ss3 = wred_sum(ss3);
  float ise = 1.f/se, is0 = 1.f/ss0, is1 = 1.f/ss1, is2 = 1.f/ss2, is3 = 1.f/ss3;
  float z0 = 0.f, z1 = 0.f, z2 = 0.f, z3 = 0.f;
  for (int base = 0; base < cnt; base += 64){
    int j = base + lane;
    if (j < cnt){
      int e = eid[s0 + j];
      float dd = d_e[e];
      float4 lg = *reinterpret_cast<const float4*>(logit + 4*(size_t)e);
      float ae = __expf(-dd - me) * ise;
      z0 += ae * __expf(lg.x - ms0) * is0;
      z1 += ae * __expf(lg.y - ms1) * is1;
      z2 += ae * __expf(lg.z - ms2) * is2;
      z3 += ae * __expf(lg.w - ms3) * is3;
    }
  }
  z0 = wred_sum(z0); z1 = wred_sum(z1); z2 = wred_sum(z2); z3 = wred_sum(z3);
  float iz0 = 1.f/z0, iz1 = 1.f/z1, iz2 = 1.f/z2, iz3 = 1.f/z3;
  for (int base = 0; base < cnt; base += 64){
    int j = base + lane;
    if (j < cnt){
      int e = eid[s0 + j];
      float dd = d_e[e];
      float4 lg = *reinterpret_cast<const float4*>(logit + 4*(size_t)e);
      float ae = __expf(-dd - me) * ise;
      float4 o;
      o.x = ae * __expf(lg.x - ms0) * is0 * iz0;
      o.y = ae * __expf(lg.y - ms1) * is1 * iz1;
      o.z = ae * __expf(lg.z - ms2) * is2 * iz2;
      o.w = ae * __expf(lg.w - ms3) * is3 * iz3;
      *reinterpret_cast<float4*>(att + 4*(size_t)e) = o;
    }
  }
}

// ---- copy h into node_in[:,0:64] ----
__global__ __launch_bounds__(256) void copyh_k(const float* __restrict__ h,
                                               float* __restrict__ node_in){
  int gid = blockIdx.x * 256 + threadIdx.x;
  if (gid >= NN*64) return;
  int n = gid >> 6, ch = gid & 63;
  node_in[(size_t)n*384 + ch] = h[gid];
}

// ---- per-node aggregate: cnorm = |sum coef*dirs|^2, h_agg = sum he*att ----
__global__ __launch_bounds__(256) void agg_k(const int* __restrict__ offs,
                                             const int* __restrict__ eid,
                                             const u16* __restrict__ coef,
                                             const float* __restrict__ he,
                                             const float* __restrict__ att,
                                             const float* __restrict__ dirs,
                                             float* __restrict__ cnorm,
                                             float* __restrict__ node_in){
  int node = blockIdx.x;
  int c = threadIdx.x;
  int s0 = offs[node], cnt = offs[node+1] - s0;
  int q = c >> 2, hd = c & 3;
  float cs0 = 0.f, cs1 = 0.f, cs2 = 0.f, ha = 0.f;
  for (int j = 0; j < cnt; ++j){
    int e = eid[s0 + j];
    float co = bf2f(coef[(size_t)e*256 + c]);
    float hv = he[(size_t)e*64 + q] * att[(size_t)e*4 + hd];
    float d0 = dirs[3*(size_t)e], d1 = dirs[3*(size_t)e+1], d2 = dirs[3*(size_t)e+2];
    cs0 = fmaf(co, d0, cs0); cs1 = fmaf(co, d1, cs1); cs2 = fmaf(co, d2, cs2);
    ha += hv;
  }
  cnorm[(size_t)node*256 + c] = cs0*cs0 + cs1*cs1 + cs2*cs2;
  node_in[(size_t)node*384 + 64 + c] = ha;
}

// ---- graph pooling ----
__global__ __launch_bounds__(256) void segy_k(const float* __restrict__ hf,
                                              const int* __restrict__ seg,
                                              float* __restrict__ y){
  int gid = blockIdx.x * 256 + threadIdx.x;
  if (gid >= NN*64) return;
  int n = gid >> 6, ch = gid & 63;
  atomicAdd(&y[seg[n]*64 + ch], hf[gid]);
}

// ---- final head ----
__global__ void headf_k(const float* __restrict__ t2,
                        const float* __restrict__ w2,
                        const float* __restrict__ b2,
                        float* __restrict__ out){
  int s = threadIdx.x;
  if (s >= NSEG) return;
  float acc = b2[0];
  for (int k = 0; k < 64; ++k) acc = fmaf(t2[s*64 + k], w2[k], acc);
  out[s] = acc;
}

extern "C" void kernel_launch(void* const* d_in, const int* in_sizes, int n_in,
                              void* d_out, int out_size, void* d_ws, size_t ws_size,
                              hipStream_t stream) {
  (void)in_sizes; (void)n_in; (void)out_size; (void)ws_size;
  const float* in_i       = (const float*)d_in[0];
  const float* in_x       = (const float*)d_in[1];
  const float* emb_in_w   = (const float*)d_in[2];
  const float* emb_in_b   = (const float*)d_in[3];
  const float* edge_in_w  = (const float*)d_in[4];
  const float* edge_in_b  = (const float*)d_in[5];
  const float* rbf_means  = (const float*)d_in[6];
  const float* rbf_betas  = (const float*)d_in[7];
  const float* edge_o_w1  = (const float*)d_in[8];
  const float* edge_o_b1  = (const float*)d_in[9];
  const float* edge_o_w2  = (const float*)d_in[10];
  const float* edge_o_b2  = (const float*)d_in[11];
  const float* sem_w      = (const float*)d_in[12];
  const float* sem_b      = (const float*)d_in[13];
  const float* xmix_w     = (const float*)d_in[14];
  const float* pn_w1      = (const float*)d_in[15];
  const float* pn_b1      = (const float*)d_in[16];
  const float* pn_w2      = (const float*)d_in[17];
  const float* pn_b2      = (const float*)d_in[18];
  const float* node_w1    = (const float*)d_in[19];
  const float* node_b1    = (const float*)d_in[20];
  const float* node_w2    = (const float*)d_in[21];
  const float* node_b2    = (const float*)d_in[22];
  const float* emb_o_w1   = (const float*)d_in[23];
  const float* emb_o_b1   = (const float*)d_in[24];
  const float* emb_o_w2   = (const float*)d_in[25];
  const float* emb_o_b2   = (const float*)d_in[26];
  const float* head_w1    = (const float*)d_in[27];
  const float* head_b1    = (const float*)d_in[28];
  const float* head_w2    = (const float*)d_in[29];
  const float* head_b2    = (const float*)d_in[30];
  const int*   edges      = (const int*)d_in[31];
  const int*   segs       = (const int*)d_in[32];
  float* out = (float*)d_out;

  // workspace carve-up (256B aligned)
  char* base = (char*)d_ws;
  size_t off = 0;
  auto alloc = [&](size_t bytes) -> void* {
    void* p = base + off;
    off += (bytes + 255) & ~(size_t)255;
    return p;
  };
  float* d_e    = (float*)alloc((size_t)EN*4);
  float* dirs   = (float*)alloc((size_t)EN*3*4);
  float* rbf_b  = (float*)alloc((size_t)EN*4);
  float* hA     = (float*)alloc((size_t)NN*64*4);
  float* hB     = (float*)alloc((size_t)NN*64*4);
  float* bufA   = (float*)alloc((size_t)EN*256*4);  // ein fp32 | hea bf16 + coef bf16
  float* he     = (float*)alloc((size_t)EN*64*4);
  float* t_edge = (float*)alloc((size_t)EN*64*4);
  float* logit  = (float*)alloc((size_t)EN*4*4);
  float* att    = (float*)alloc((size_t)EN*4*4);
  float* cnorm  = (float*)alloc((size_t)NN*256*4);
  float* node_in= (float*)alloc((size_t)NN*384*4);
  float* pn_t   = (float*)alloc((size_t)NN*64*4);
  float* t_node = (float*)alloc((size_t)NN*64*4);
  float* y      = (float*)alloc((size_t)NSEG*64*4);
  float* t2     = (float*)alloc((size_t)NSEG*64*4);
  u16* xmix_t   = (u16*)alloc((size_t)DEPTH*256*256*2);
  int* counts   = (int*)alloc((size_t)NN*4);
  int* cursor   = (int*)alloc((size_t)NN*4);
  int* offs     = (int*)alloc((size_t)(NN+1)*4);
  int* eid      = (int*)alloc((size_t)EN*4);
  // aliases inside bufA (time-disjoint with ein):
  float* ein  = bufA;                                   // E x 180 fp32
  u16*   hea  = (u16*)bufA;                             // E x 256 bf16 (first half)
  u16*   coef = (u16*)bufA + (size_t)EN*256;            // E x 256 bf16 (second half)

  hipMemsetAsync(counts, 0, (size_t)NN*4, stream);
  hipMemsetAsync(cursor, 0, (size_t)NN*4, stream);
  hipMemsetAsync(y, 0, (size_t)NSEG*64*4, stream);

  geom_k<<<(EN+255)/256, 256, 0, stream>>>(edges, in_x, d_e, dirs, rbf_b, counts);
  scan_k<<<1, 256, 0, stream>>>(counts, offs);
  fill_k<<<(EN+255)/256, 256, 0, stream>>>(edges, offs, cursor, eid);
  convx_k<<<dim3(256, DEPTH), 256, 0, stream>>>(xmix_w, xmix_t);

  // h = i @ emb_in_w + b
  gemm_k<0><<<dim3((NN+15)/16, 1), 256, 0, stream>>>(
      in_i, 16, emb_in_w, 64, emb_in_b, hA, 64, 0, NN, 64, 16,
      nullptr, nullptr, nullptr);

  float* hcur = hA;
  float* hnext = hB;
  for (int l = 0; l < DEPTH; ++l){
    const float* Win  = edge_in_w + (size_t)l*128*50;
    const float* bin  = edge_in_b + (size_t)l*50;
    const float* mean = rbf_means + (size_t)l*50;
    const float* beta = rbf_betas + (size_t)l*50;
    const float* W1   = edge_o_w1 + (size_t)l*179*64;
    const float* b1   = edge_o_b1 + (size_t)l*64;
    const float* W2   = edge_o_w2 + (size_t)l*64*64;
    const float* b2   = edge_o_b2 + (size_t)l*64;
    const float* sw   = sem_w + (size_t)l*64*4;
    const float* sb   = sem_b + (size_t)l*4;
    const u16*   xwt  = xmix_t + (size_t)l*256*256;
    const float* pw1  = pn_w1 + (size_t)l*256*64;
    const float* pb1  = pn_b1 + (size_t)l*64;
    const float* pw2  = pn_w2 + (size_t)l*64*64;
    const float* pb2  = pn_b2 + (size_t)l*64;
    const float* nw1  = node_w1 + (size_t)l*384*64;
    const float* nb1  = node_b1 + (size_t)l*64;
    const float* nw2  = node_w2 + (size_t)l*64*64;
    const float* nb2  = node_b2 + (size_t)l*64;

    build_ein_k<<<(EN*128)/256, 256, 0, stream>>>(edges, hcur, d_e, ein);
    // hm -> rbf*hm written into ein[:,128:178]
    gemm_k<3><<<dim3(EN/16, 1), 256, 0, stream>>>(
        ein, 180, Win, 50, bin, ein, 180, 128, EN, 50, 128,
        rbf_b, mean, beta);
    // t = silu(ein @ W1 + b1)   (K=179 covers [hc, rbf*hm, d])
    gemm_k<1><<<dim3(EN/16, 1), 256, 0, stream>>>(
        ein, 180, W1, 64, b1, t_edge, 64, 0, EN, 64, 179,
        nullptr, nullptr, nullptr);
    // he = t @ W2 + b2
    gemm_k<0><<<dim3(EN/16, 1), 256, 0, stream>>>(
        t_edge, 64, W2, 64, b2, he, 64, 0, EN, 64, 64,
        nullptr, nullptr, nullptr);
    sem_k<<<(EN+63)/64, 256, 0, stream>>>(he, sw, sb, logit);
    att_k<<<(NN+3)/4, 256, 0, stream>>>(offs, eid, d_e, logit, att);
    // hea (bf16) then coef = tanh(hea @ xmix) via MFMA
    hea_k<<<(EN*64)/256, 256, 0, stream>>>(he, att, hea);
    bgemm_tanh_k<<<dim3((EN+63)/64, 4), 256, 0, stream>>>(
        hea, 256, xwt, 256, coef, 256, EN, 256);
    copyh_k<<<(NN*64)/256, 256, 0, stream>>>(hcur, node_in);
    agg_k<<<NN, 256, 0, stream>>>(offs, eid, coef, he, att, dirs, cnorm, node_in);
    // h_comb = silu(silu(cnorm@pn_w1+b1)@pn_w2+b2) -> node_in[:,320:384]
    gemm_k<1><<<dim3(NN/16, 1), 256, 0, stream>>>(
        cnorm, 256, pw1, 64, pb1, pn_t, 64, 0, NN, 64, 256,
        nullptr, nullptr, nullptr);
    gemm_k<1><<<dim3(NN/16, 1), 256, 0, stream>>>(
        pn_t, 64, pw2, 64, pb2, node_in, 384, 320, NN, 64, 64,
        nullptr, nullptr, nullptr);
    // node update
    gemm_k<1><<<dim3(NN/16, 1), 256, 0, stream>>>(
        node_in, 384, nw1, 64, nb1, t_node, 64, 0, NN, 64, 384,
        nullptr, nullptr, nullptr);
    gemm_k<4><<<dim3(NN/16, 1), 256, 0, stream>>>(
        t_node, 64, nw2, 64, nb2, hnext, 64, 0, NN, 64, 64,
        hcur, nullptr, nullptr);
    float* tmp = hcur; hcur = hnext; hnext = tmp;
  }

  // output head
  gemm_k<1><<<dim3(NN/16, 1), 256, 0, stream>>>(
      hcur, 64, emb_o_w1, 64, emb_o_b1, t_node, 64, 0, NN, 64, 64,
      nullptr, nullptr, nullptr);
  gemm_k<0><<<dim3(NN/16, 1), 256, 0, stream>>>(
      t_node, 64, emb_o_w2, 64, emb_o_b2, hnext, 64, 0, NN, 64, 64,
      nullptr, nullptr, nullptr);
  segy_k<<<(NN*64)/256, 256, 0, stream>>>(hnext, segs, y);
  gemm_k<1><<<dim3((NSEG+15)/16, 1), 256, 0, stream>>>(
      y, 64, head_w1, 64, head_b1, t2, 64, 0, NSEG, 64, 64,
      nullptr, nullptr, nullptr);
  headf_k<<<1, 128, 0, stream>>>(t2, head_w2, head_b2, out);
}

// Round 3
// 1489.735 us; speedup vs baseline: 4.7913x; 2.7992x over previous
//
#include <hip/hip_runtime.h>
#include <hip/hip_bf16.h>

// ---- problem constants ----
constexpr int EN   = 100000;  // edges
constexpr int NN   = 10000;   // nodes
constexpr int DEPTH = 6;
constexpr int NSEG = 100;

typedef unsigned short u16;
typedef __bf16 bf16x8 __attribute__((ext_vector_type(8)));
typedef float  f32x4  __attribute__((ext_vector_type(4)));

__device__ inline float wred_max(float v){
#pragma unroll
  for (int o = 32; o > 0; o >>= 1) v = fmaxf(v, __shfl_xor(v, o, 64));
  return v;
}
__device__ inline float wred_sum(float v){
#pragma unroll
  for (int o = 32; o > 0; o >>= 1) v += __shfl_xor(v, o, 64);
  return v;
}
__device__ inline float siluf(float x){ return x / (1.f + __expf(-x)); }
__device__ inline u16 f2bf(float x){
  __hip_bfloat16 h = __float2bfloat16(x);
  return *reinterpret_cast<u16*>(&h);
}
__device__ inline float bf2f(u16 u){
  union { float f; unsigned int ui; } v; v.ui = ((unsigned int)u) << 16; return v.f;
}

// ---- geometry + dst histogram ----
__global__ __launch_bounds__(256) void geom_k(const int* __restrict__ edges,
                                              const float* __restrict__ x,
                                              float* __restrict__ d_e,
                                              float* __restrict__ dirs,
                                              float* __restrict__ rbf_b,
                                              int* __restrict__ counts){
  int e = blockIdx.x * 256 + threadIdx.x;
  if (e >= EN) return;
  int dst = edges[2*e], src = edges[2*e+1];
  float dx = x[dst*3+0] - x[src*3+0];
  float dy = x[dst*3+1] - x[src*3+1];
  float dz = x[dst*3+2] - x[src*3+2];
  float dd = sqrtf(dx*dx + dy*dy + dz*dz + 1e-10f);
  d_e[e] = dd;
  float inv = 1.f / (dd + 1e-5f);
  dirs[3*e+0] = dx*inv; dirs[3*e+1] = dy*inv; dirs[3*e+2] = dz*inv;
  rbf_b[e] = __expf(-dd);
  atomicAdd(&counts[dst], 1);
}

// ---- exclusive scan of counts -> offsets (single block) ----
__global__ __launch_bounds__(256) void scan_k(const int* __restrict__ counts,
                                              int* __restrict__ offs){
  __shared__ int part[256];
  const int CH = (NN + 255) / 256;  // 40
  int t = threadIdx.x;
  int s = 0;
  for (int j = 0; j < CH; ++j){ int idx = t*CH + j; if (idx < NN) s += counts[idx]; }
  part[t] = s;
  __syncthreads();
  if (t == 0){
    int run = 0;
    for (int i = 0; i < 256; ++i){ int v = part[i]; part[i] = run; run += v; }
    offs[NN] = run;
  }
  __syncthreads();
  int run = part[t];
  for (int j = 0; j < CH; ++j){
    int idx = t*CH + j;
    if (idx < NN){ offs[idx] = run; run += counts[idx]; }
  }
}

// ---- CSR fill ----
__global__ __launch_bounds__(256) void fill_k(const int* __restrict__ edges,
                                              const int* __restrict__ offs,
                                              int* __restrict__ cursor,
                                              int* __restrict__ eid){
  int e = blockIdx.x * 256 + threadIdx.x;
  if (e >= EN) return;
  int dst = edges[2*e];
  int pos = offs[dst] + atomicAdd(&cursor[dst], 1);
  eid[pos] = e;
}

// ---- once per call: ein[e][178]=d (bf16), ein[e][179:192]=0 ----
__global__ __launch_bounds__(256) void eind_k(const float* __restrict__ d_e,
                                              u16* __restrict__ ein){
  int gid = blockIdx.x * 256 + threadIdx.x;
  int e = gid >> 4, j = gid & 15;
  if (e >= EN || j >= 14) return;
  ein[(size_t)e*192 + 178 + j] = (j == 0) ? f2bf(d_e[e]) : (u16)0;
}

// ---- h (fp32) -> hbf (bf16 cache) + node_in[:,0:64] ----
__global__ __launch_bounds__(256) void h2b_k(const float* __restrict__ h,
                                             u16* __restrict__ hbf,
                                             u16* __restrict__ node_in){
  int gid = blockIdx.x * 256 + threadIdx.x;
  if (gid >= NN*64) return;
  int n = gid >> 6, ch = gid & 63;
  u16 b = f2bf(h[gid]);
  hbf[gid] = b;
  node_in[(size_t)n*384 + ch] = b;
}

// ---- build edge input (bf16): ein[e][0:128] = concat(hbf[dst], hbf[src]) ----
__global__ __launch_bounds__(256) void build_ein_k(const int* __restrict__ edges,
                                                   const u16* __restrict__ hbf,
                                                   u16* __restrict__ ein){
  int gid = blockIdx.x * 256 + threadIdx.x;
  int e = gid >> 4, j = gid & 15;
  if (e >= EN) return;
  int node = (j < 8) ? edges[2*e] : edges[2*e+1];
  int c8 = (j & 7) * 8;
  uint4 v = *reinterpret_cast<const uint4*>(hbf + (size_t)node*64 + c8);
  *reinterpret_cast<uint4*>(ein + (size_t)e*192 + j*8) = v;
}

// ---- generic weight convert+transpose: dst[l][n][k] = bf16(src[l][k][n]) ----
__global__ void convw_k(const float* __restrict__ src, int K, int N, size_t sStride,
                        u16* __restrict__ dst, int Kpad, int Npad, size_t dStride){
  int idx = blockIdx.x * 256 + threadIdx.x;
  if (idx >= Npad*Kpad) return;
  int n = idx / Kpad, k = idx - n*Kpad;
  float v = (k < K && n < N) ? src[blockIdx.y*sStride + (size_t)k*N + n] : 0.f;
  dst[blockIdx.y*dStride + idx] = f2bf(v);
}

// ---- generic bf16 MFMA GEMM, 64xM-tile x (CT*16)-N-tile, BK=32, 4 waves ----
// EPI: 0=bias fp32out, 1=silu bf16out, 2=tanh bf16out, 3=rbf bf16out,
//      4=resid+silu fp32out, 6=bias bf16out
template<int EPI, int CT>
__global__ __launch_bounds__(256) void bgemm_k(const u16* __restrict__ A, int lda,
                                               const u16* __restrict__ Wt, int ldw,
                                               const float* __restrict__ bias,
                                               float* __restrict__ outf,
                                               u16* __restrict__ outb,
                                               int ldo, int ocol,
                                               int M, int Nout, int K,
                                               const float* __restrict__ e0,
                                               const float* __restrict__ e1,
                                               const float* __restrict__ e2){
  __shared__ u16 A_s[64*32];
  __shared__ u16 B_s[CT*16*32];
  const int tid  = threadIdx.x;
  const int lane = tid & 63;
  const int wave = tid >> 6;
  const int m0   = blockIdx.x * 64;
  const int n0   = blockIdx.y * (CT*16);
  const int l15  = lane & 15;
  const int kq   = (lane >> 4) * 8;

  const int srow = tid >> 2;          // 0..63
  const int sk   = (tid & 3) * 8;     // 0,8,16,24
  const int arow = min(m0 + srow, M - 1);
  const size_t a_base = (size_t)arow * lda + sk;

  f32x4 acc[CT];
#pragma unroll
  for (int c = 0; c < CT; ++c) acc[c] = (f32x4){0.f, 0.f, 0.f, 0.f};

  for (int kc = 0; kc < K; kc += 32){
    *reinterpret_cast<uint4*>(A_s + srow*32 + sk) =
        *reinterpret_cast<const uint4*>(A + a_base + kc);
#pragma unroll
    for (int i = 0; i < CT/4; ++i){
      int r = srow + i*64;
      *reinterpret_cast<uint4*>(B_s + r*32 + sk) =
          *reinterpret_cast<const uint4*>(Wt + (size_t)(n0 + r)*ldw + kc + sk);
    }
    __syncthreads();
    bf16x8 af = *reinterpret_cast<const bf16x8*>(A_s + (wave*16 + l15)*32 + kq);
#pragma unroll
    for (int c = 0; c < CT; ++c){
      bf16x8 bf = *reinterpret_cast<const bf16x8*>(B_s + (c*16 + l15)*32 + kq);
      acc[c] = __builtin_amdgcn_mfma_f32_16x16x32_bf16(af, bf, acc[c], 0, 0, 0);
    }
    __syncthreads();
  }

  // C/D layout: col = lane&15, row = (lane>>4)*4 + r
  const int rloc = wave*16 + ((lane >> 4) << 2);
#pragma unroll
  for (int c = 0; c < CT; ++c){
    int n = n0 + c*16 + l15;
    if (n >= Nout) continue;
    float b = bias ? bias[n] : 0.f;
#pragma unroll
    for (int r = 0; r < 4; ++r){
      int m = m0 + rloc + r;
      if (m >= M) continue;
      float a = acc[c][r];
      if (EPI == 0){
        outf[(size_t)m*ldo + ocol + n] = a + b;
      } else if (EPI == 1){
        outb[(size_t)m*ldo + ocol + n] = f2bf(siluf(a + b));
      } else if (EPI == 2){
        outb[(size_t)m*ldo + ocol + n] = f2bf(tanhf(a));
      } else if (EPI == 3){
        float df = e0[m] - e1[n];
        outb[(size_t)m*ldo + ocol + n] = f2bf(__expf(-e2[n]*df*df) * (a + b));
      } else if (EPI == 4){
        outf[(size_t)m*ldo + ocol + n] = e0[(size_t)m*64 + n] + siluf(a + b);
      } else {
        outb[(size_t)m*ldo + ocol + n] = f2bf(a + b);
      }
    }
  }
}

// ---- generic tiled fp32 GEMM (small M / K=16 cases) ----
// EPI: 0=none 1=silu
template<int EPI>
__global__ __launch_bounds__(256) void gemm_k(const float* __restrict__ A, int lda,
                                              const float* __restrict__ W, int ldw,
                                              const float* __restrict__ bias,
                                              float* __restrict__ out, int ldo, int ocol,
                                              int M, int N, int K){
  __shared__ float w_s[128*64];
  const int tid  = threadIdx.x;
  const int nl   = tid & 63;
  const int rg   = tid >> 6;
  const int col0 = blockIdx.y * 64;
  const int m0   = blockIdx.x * 16 + rg * 4;
  float acc[4] = {0.f, 0.f, 0.f, 0.f};
  const float* ar[4];
#pragma unroll
  for (int r = 0; r < 4; ++r){
    int mr = min(m0 + r, M - 1);
    ar[r] = A + (size_t)mr * lda;
  }
  for (int kc = 0; kc < K; kc += 128){
    int kn = min(128, K - kc);
    for (int idx = tid; idx < 128*64; idx += 256){
      int kk = idx >> 6, nn = idx & 63;
      int gn = col0 + nn;
      w_s[idx] = (kk < kn && gn < N) ? W[(size_t)(kc+kk)*ldw + gn] : 0.f;
    }
    __syncthreads();
    for (int k = 0; k < kn; ++k){
      float wv = w_s[k*64 + nl];
#pragma unroll
      for (int r = 0; r < 4; ++r) acc[r] = fmaf(ar[r][kc + k], wv, acc[r]);
    }
    __syncthreads();
  }
  int n = col0 + nl;
  if (n >= N) return;
  float b = bias ? bias[n] : 0.f;
#pragma unroll
  for (int r = 0; r < 4; ++r){
    int m = m0 + r;
    if (m >= M) break;
    float a = acc[r] + b;
    out[(size_t)m*ldo + ocol + n] = (EPI == 1) ? siluf(a) : a;
  }
}

// ---- sem head logits + celu(alpha=2), he in bf16 ----
__global__ __launch_bounds__(256) void sem_k(const u16* __restrict__ he,
                                             const float* __restrict__ sw,
                                             const float* __restrict__ sb,
                                             float* __restrict__ logit){
  __shared__ float tile[64*65];
  int e0 = blockIdx.x * 64;
  for (int idx = threadIdx.x; idx < 64*16; idx += 256){
    int r = idx >> 4, c4 = (idx & 15) * 4;
    int e = e0 + r;
    ushort4 u = (e < EN) ? *reinterpret_cast<const ushort4*>(he + (size_t)e*64 + c4)
                         : (ushort4){0,0,0,0};
    tile[r*65 + c4+0] = bf2f(u.x);
    tile[r*65 + c4+1] = bf2f(u.y);
    tile[r*65 + c4+2] = bf2f(u.z);
    tile[r*65 + c4+3] = bf2f(u.w);
  }
  __syncthreads();
  int er = threadIdx.x >> 2, hd = threadIdx.x & 3;
  int e = e0 + er;
  float acc = sb[hd];
#pragma unroll 8
  for (int k = 0; k < 64; ++k) acc = fmaf(tile[er*65 + k], sw[k*4 + hd], acc);
  float v = acc > 0.f ? acc : 2.f*(__expf(0.5f*acc) - 1.f);
  if (e < EN) logit[(size_t)e*4 + hd] = v;
}

// ---- per-node attention: att = norm(softmax(-d) * softmax(celu_logits)) ----
__global__ __launch_bounds__(256) void att_k(const int* __restrict__ offs,
                                             const int* __restrict__ eid,
                                             const float* __restrict__ d_e,
                                             const float* __restrict__ logit,
                                             float* __restrict__ att){
  int lane = threadIdx.x & 63;
  int node = (blockIdx.x * 256 + threadIdx.x) >> 6;
  if (node >= NN) return;
  int s0 = offs[node];
  int cnt = offs[node+1] - s0;
  if (cnt <= 0) return;
  const float NEG = -1e30f;
  float me = NEG, ms0 = NEG, ms1 = NEG, ms2 = NEG, ms3 = NEG;
  for (int base = 0; base < cnt; base += 64){
    int j = base + lane;
    if (j < cnt){
      int e = eid[s0 + j];
      float dd = d_e[e];
      me = fmaxf(me, -dd);
      float4 lg = *reinterpret_cast<const float4*>(logit + 4*(size_t)e);
      ms0 = fmaxf(ms0, lg.x); ms1 = fmaxf(ms1, lg.y);
      ms2 = fmaxf(ms2, lg.z); ms3 = fmaxf(ms3, lg.w);
    }
  }
  me = wred_max(me); ms0 = wred_max(ms0); ms1 = wred_max(ms1);
  ms2 = wred_max(ms2); ms3 = wred_max(ms3);
  float se = 0.f, ss0 = 0.f, ss1 = 0.f, ss2 = 0.f, ss3 = 0.f;
  for (int base = 0; base < cnt; base += 64){
    int j = base + lane;
    if (j < cnt){
      int e = eid[s0 + j];
      float dd = d_e[e];
      float4 lg = *reinterpret_cast<const float4*>(logit + 4*(size_t)e);
      se  += __expf(-dd - me);
      ss0 += __expf(lg.x - ms0); ss1 += __expf(lg.y - ms1);
      ss2 += __expf(lg.z - ms2); ss3 += __expf(lg.w - ms3);
    }
  }
  se = wred_sum(se); ss0 = wred_sum(ss0); ss1 = wred_sum(ss1);
  ss2 = wred_sum(ss2); ss3 = wred_sum(ss3);
  float ise = 1.f/se, is0 = 1.f/ss0, is1 = 1.f/ss1, is2 = 1.f/ss2, is3 = 1.f/ss3;
  float z0 = 0.f, z1 = 0.f, z2 = 0.f, z3 = 0.f;
  for (int base = 0; base < cnt; base += 64){
    int j = base + lane;
    if (j < cnt){
      int e = eid[s0 + j];
      float dd = d_e[e];
      float4 lg = *reinterpret_cast<const float4*>(logit + 4*(size_t)e);
      float ae = __expf(-dd - me) * ise;
      z0 += ae * __expf(lg.x - ms0) * is0;
      z1 += ae * __expf(lg.y - ms1) * is1;
      z2 += ae * __expf(lg.z - ms2) * is2;
      z3 += ae * __expf(lg.w - ms3) * is3;
    }
  }
  z0 = wred_sum(z0); z1 = wred_sum(z1); z2 = wred_sum(z2); z3 = wred_sum(z3);
  float iz0 = 1.f/z0, iz1 = 1.f/z1, iz2 = 1.f/z2, iz3 = 1.f/z3;
  for (int base = 0; base < cnt; base += 64){
    int j = base + lane;
    if (j < cnt){
      int e = eid[s0 + j];
      float dd = d_e[e];
      float4 lg = *reinterpret_cast<const float4*>(logit + 4*(size_t)e);
      float ae = __expf(-dd - me) * ise;
      float4 o;
      o.x = ae * __expf(lg.x - ms0) * is0 * iz0;
      o.y = ae * __expf(lg.y - ms1) * is1 * iz1;
      o.z = ae * __expf(lg.z - ms2) * is2 * iz2;
      o.w = ae * __expf(lg.w - ms3) * is3 * iz3;
      *reinterpret_cast<float4*>(att + 4*(size_t)e) = o;
    }
  }
}

// ---- hea[e][q*4+hd] = bf16(he[e][q]*att[e][hd]) ----
__global__ __launch_bounds__(256) void hea_k(const u16* __restrict__ he,
                                             const float* __restrict__ att,
                                             u16* __restrict__ hea){
  int gid = blockIdx.x * 256 + threadIdx.x;
  if (gid >= EN*64) return;
  int e = gid >> 6, q = gid & 63;
  float hv = bf2f(he[(size_t)e*64 + q]);
  float4 a = *reinterpret_cast<const float4*>(att + (size_t)e*4);
  ushort4 pk;
  pk.x = f2bf(hv * a.x);
  pk.y = f2bf(hv * a.y);
  pk.z = f2bf(hv * a.z);
  pk.w = f2bf(hv * a.w);
  *reinterpret_cast<ushort4*>(hea + (size_t)e*256 + q*4) = pk;
}

// ---- per-node aggregate: cnorm = |sum coef*dirs|^2 (bf16), h_agg = sum hea ----
__global__ __launch_bounds__(256) void agg_k(const int* __restrict__ offs,
                                             const int* __restrict__ eid,
                                             const u16* __restrict__ coef,
                                             const u16* __restrict__ hea,
                                             const float* __restrict__ dirs,
                                             u16* __restrict__ cnorm,
                                             u16* __restrict__ node_in){
  int node = blockIdx.x;
  int c = threadIdx.x;
  int s0 = offs[node], cnt = offs[node+1] - s0;
  float cs0 = 0.f, cs1 = 0.f, cs2 = 0.f, ha = 0.f;
  for (int j = 0; j < cnt; ++j){
    int e = eid[s0 + j];
    float co = bf2f(coef[(size_t)e*256 + c]);
    float hv = bf2f(hea[(size_t)e*256 + c]);
    float d0 = dirs[3*(size_t)e], d1 = dirs[3*(size_t)e+1], d2 = dirs[3*(size_t)e+2];
    cs0 = fmaf(co, d0, cs0); cs1 = fmaf(co, d1, cs1); cs2 = fmaf(co, d2, cs2);
    ha += hv;
  }
  cnorm[(size_t)node*256 + c] = f2bf(cs0*cs0 + cs1*cs1 + cs2*cs2);
  node_in[(size_t)node*384 + 64 + c] = f2bf(ha);
}

// ---- graph pooling ----
__global__ __launch_bounds__(256) void segy_k(const float* __restrict__ hf,
                                              const int* __restrict__ seg,
                                              float* __restrict__ y){
  int gid = blockIdx.x * 256 + threadIdx.x;
  if (gid >= NN*64) return;
  int n = gid >> 6, ch = gid & 63;
  atomicAdd(&y[seg[n]*64 + ch], hf[gid]);
}

// ---- final head ----
__global__ void headf_k(const float* __restrict__ t2,
                        const float* __restrict__ w2,
                        const float* __restrict__ b2,
                        float* __restrict__ out){
  int s = threadIdx.x;
  if (s >= NSEG) return;
  float acc = b2[0];
  for (int k = 0; k < 64; ++k) acc = fmaf(t2[s*64 + k], w2[k], acc);
  out[s] = acc;
}

extern "C" void kernel_launch(void* const* d_in, const int* in_sizes, int n_in,
                              void* d_out, int out_size, void* d_ws, size_t ws_size,
                              hipStream_t stream) {
  (void)in_sizes; (void)n_in; (void)out_size; (void)ws_size;
  const float* in_i       = (const float*)d_in[0];
  const float* in_x       = (const float*)d_in[1];
  const float* emb_in_w   = (const float*)d_in[2];
  const float* emb_in_b   = (const float*)d_in[3];
  const float* edge_in_w  = (const float*)d_in[4];
  const float* edge_in_b  = (const float*)d_in[5];
  const float* rbf_means  = (const float*)d_in[6];
  const float* rbf_betas  = (const float*)d_in[7];
  const float* edge_o_w1  = (const float*)d_in[8];
  const float* edge_o_b1  = (const float*)d_in[9];
  const float* edge_o_w2  = (const float*)d_in[10];
  const float* edge_o_b2  = (const float*)d_in[11];
  const float* sem_w      = (const float*)d_in[12];
  const float* sem_b      = (const float*)d_in[13];
  const float* xmix_w     = (const float*)d_in[14];
  const float* pn_w1      = (const float*)d_in[15];
  const float* pn_b1      = (const float*)d_in[16];
  const float* pn_w2      = (const float*)d_in[17];
  const float* pn_b2      = (const float*)d_in[18];
  const float* node_w1    = (const float*)d_in[19];
  const float* node_b1    = (const float*)d_in[20];
  const float* node_w2    = (const float*)d_in[21];
  const float* node_b2    = (const float*)d_in[22];
  const float* emb_o_w1   = (const float*)d_in[23];
  const float* emb_o_b1   = (const float*)d_in[24];
  const float* emb_o_w2   = (const float*)d_in[25];
  const float* emb_o_b2   = (const float*)d_in[26];
  const float* head_w1    = (const float*)d_in[27];
  const float* head_b1    = (const float*)d_in[28];
  const float* head_w2    = (const float*)d_in[29];
  const float* head_b2    = (const float*)d_in[30];
  const int*   edges      = (const int*)d_in[31];
  const int*   segs       = (const int*)d_in[32];
  float* out = (float*)d_out;

  // workspace carve-up (256B aligned)
  char* base = (char*)d_ws;
  size_t off = 0;
  auto alloc = [&](size_t bytes) -> void* {
    void* p = base + off;
    off += (bytes + 255) & ~(size_t)255;
    return p;
  };
  float* d_e    = (float*)alloc((size_t)EN*4);
  float* dirs   = (float*)alloc((size_t)EN*3*4);
  float* rbf_b  = (float*)alloc((size_t)EN*4);
  float* hA     = (float*)alloc((size_t)NN*64*4);
  float* hB     = (float*)alloc((size_t)NN*64*4);
  u16*   ein    = (u16*)alloc((size_t)EN*192*2);   // bf16 edge input
  u16*   t_edge = (u16*)alloc((size_t)EN*64*2);
  u16*   he     = (u16*)alloc((size_t)EN*64*2);
  u16*   hea    = (u16*)alloc((size_t)EN*256*2);
  u16*   coef   = (u16*)alloc((size_t)EN*256*2);
  float* logit  = (float*)alloc((size_t)EN*4*4);
  float* att    = (float*)alloc((size_t)EN*4*4);
  u16*   hbf    = (u16*)alloc((size_t)NN*64*2);
  u16*   node_in= (u16*)alloc((size_t)NN*384*2);
  u16*   cnorm  = (u16*)alloc((size_t)NN*256*2);
  u16*   pn_t   = (u16*)alloc((size_t)NN*64*2);
  u16*   tnb    = (u16*)alloc((size_t)NN*64*2);
  float* y      = (float*)alloc((size_t)NSEG*64*4);
  float* t2     = (float*)alloc((size_t)NSEG*64*4);
  // bf16 transposed weights
  u16* winb  = (u16*)alloc((size_t)DEPTH*64*128*2);
  u16* w1b   = (u16*)alloc((size_t)DEPTH*64*192*2);
  u16* w2b   = (u16*)alloc((size_t)DEPTH*64*64*2);
  u16* xwb   = (u16*)alloc((size_t)DEPTH*256*256*2);
  u16* pw1b  = (u16*)alloc((size_t)DEPTH*64*256*2);
  u16* pw2b  = (u16*)alloc((size_t)DEPTH*64*64*2);
  u16* nw1b  = (u16*)alloc((size_t)DEPTH*64*384*2);
  u16* nw2b  = (u16*)alloc((size_t)DEPTH*64*64*2);
  int* counts   = (int*)alloc((size_t)NN*4);
  int* cursor   = (int*)alloc((size_t)NN*4);
  int* offs     = (int*)alloc((size_t)(NN+1)*4);
  int* eid      = (int*)alloc((size_t)EN*4);
  // fp32 scratch for final head, aliased over ein (dead by then)
  float* t_node = (float*)ein;

  hipMemsetAsync(counts, 0, (size_t)NN*4, stream);
  hipMemsetAsync(cursor, 0, (size_t)NN*4, stream);
  hipMemsetAsync(y, 0, (size_t)NSEG*64*4, stream);

  geom_k<<<(EN+255)/256, 256, 0, stream>>>(edges, in_x, d_e, dirs, rbf_b, counts);
  scan_k<<<1, 256, 0, stream>>>(counts, offs);
  fill_k<<<(EN+255)/256, 256, 0, stream>>>(edges, offs, cursor, eid);
  eind_k<<<(EN*16+255)/256, 256, 0, stream>>>(d_e, ein);

  // weight conversions (once per call)
  convw_k<<<dim3(32,  DEPTH), 256, 0, stream>>>(edge_in_w, 128, 50, (size_t)128*50, winb, 128, 64, (size_t)64*128);
  convw_k<<<dim3(48,  DEPTH), 256, 0, stream>>>(edge_o_w1, 179, 64, (size_t)179*64, w1b,  192, 64, (size_t)64*192);
  convw_k<<<dim3(16,  DEPTH), 256, 0, stream>>>(edge_o_w2,  64, 64, (size_t)64*64,  w2b,   64, 64, (size_t)64*64);
  convw_k<<<dim3(256, DEPTH), 256, 0, stream>>>(xmix_w,    256,256, (size_t)256*256,xwb,  256,256, (size_t)256*256);
  convw_k<<<dim3(64,  DEPTH), 256, 0, stream>>>(pn_w1,     256, 64, (size_t)256*64, pw1b, 256, 64, (size_t)64*256);
  convw_k<<<dim3(16,  DEPTH), 256, 0, stream>>>(pn_w2,      64, 64, (size_t)64*64,  pw2b,  64, 64, (size_t)64*64);
  convw_k<<<dim3(96,  DEPTH), 256, 0, stream>>>(node_w1,   384, 64, (size_t)384*64, nw1b, 384, 64, (size_t)64*384);
  convw_k<<<dim3(16,  DEPTH), 256, 0, stream>>>(node_w2,    64, 64, (size_t)64*64,  nw2b,  64, 64, (size_t)64*64);

  // h = i @ emb_in_w + b   (fp32, K=16)
  gemm_k<0><<<dim3((NN+15)/16, 1), 256, 0, stream>>>(
      in_i, 16, emb_in_w, 64, emb_in_b, hA, 64, 0, NN, 64, 16);

  const int EB = (EN + 63) / 64;   // 1563
  const int NB = (NN + 63) / 64;   // 157

  float* hcur = hA;
  float* hnext = hB;
  for (int l = 0; l < DEPTH; ++l){
    const float* bin  = edge_in_b + (size_t)l*50;
    const float* mean = rbf_means + (size_t)l*50;
    const float* beta = rbf_betas + (size_t)l*50;
    const float* b1   = edge_o_b1 + (size_t)l*64;
    const float* b2   = edge_o_b2 + (size_t)l*64;
    const float* sw   = sem_w + (size_t)l*64*4;
    const float* sb   = sem_b + (size_t)l*4;
    const float* pb1  = pn_b1 + (size_t)l*64;
    const float* pb2  = pn_b2 + (size_t)l*64;
    const float* nb1  = node_b1 + (size_t)l*64;
    const float* nb2  = node_b2 + (size_t)l*64;
    const u16* Winb = winb + (size_t)l*64*128;
    const u16* W1b  = w1b  + (size_t)l*64*192;
    const u16* W2b  = w2b  + (size_t)l*64*64;
    const u16* Xwb  = xwb  + (size_t)l*256*256;
    const u16* P1b  = pw1b + (size_t)l*64*256;
    const u16* P2b  = pw2b + (size_t)l*64*64;
    const u16* N1b  = nw1b + (size_t)l*64*384;
    const u16* N2b  = nw2b + (size_t)l*64*64;

    h2b_k<<<(NN*64)/256, 256, 0, stream>>>(hcur, hbf, node_in);
    build_ein_k<<<(EN*16)/256, 256, 0, stream>>>(edges, hbf, ein);
    // rbf*hm -> ein[:,128:178]
    bgemm_k<3,4><<<dim3(EB,1), 256, 0, stream>>>(
        ein, 192, Winb, 128, bin, nullptr, ein, 192, 128, EN, 50, 128,
        rbf_b, mean, beta);
    // t = silu(ein @ W1 + b1)
    bgemm_k<1,4><<<dim3(EB,1), 256, 0, stream>>>(
        ein, 192, W1b, 192, b1, nullptr, t_edge, 64, 0, EN, 64, 192,
        nullptr, nullptr, nullptr);
    // he = t @ W2 + b2 (bf16)
    bgemm_k<6,4><<<dim3(EB,1), 256, 0, stream>>>(
        t_edge, 64, W2b, 64, b2, nullptr, he, 64, 0, EN, 64, 64,
        nullptr, nullptr, nullptr);
    sem_k<<<EB, 256, 0, stream>>>(he, sw, sb, logit);
    att_k<<<(NN+3)/4, 256, 0, stream>>>(offs, eid, d_e, logit, att);
    hea_k<<<(EN*64)/256, 256, 0, stream>>>(he, att, hea);
    // coef = tanh(hea @ xmix)  (64x256 tile, single pass over A)
    bgemm_k<2,16><<<dim3(EB,1), 256, 0, stream>>>(
        hea, 256, Xwb, 256, nullptr, nullptr, coef, 256, 0, EN, 256, 256,
        nullptr, nullptr, nullptr);
    agg_k<<<NN, 256, 0, stream>>>(offs, eid, coef, hea, dirs, cnorm, node_in);
    // h_comb = silu(silu(cnorm@pn_w1+b1)@pn_w2+b2) -> node_in[:,320:384]
    bgemm_k<1,4><<<dim3(NB,1), 256, 0, stream>>>(
        cnorm, 256, P1b, 256, pb1, nullptr, pn_t, 64, 0, NN, 64, 256,
        nullptr, nullptr, nullptr);
    bgemm_k<1,4><<<dim3(NB,1), 256, 0, stream>>>(
        pn_t, 64, P2b, 64, pb2, nullptr, node_in, 384, 320, NN, 64, 64,
        nullptr, nullptr, nullptr);
    // node update
    bgemm_k<1,4><<<dim3(NB,1), 256, 0, stream>>>(
        node_in, 384, N1b, 384, nb1, nullptr, tnb, 64, 0, NN, 64, 384,
        nullptr, nullptr, nullptr);
    bgemm_k<4,4><<<dim3(NB,1), 256, 0, stream>>>(
        tnb, 64, N2b, 64, nb2, hnext, nullptr, 64, 0, NN, 64, 64,
        hcur, nullptr, nullptr);
    float* tmp = hcur; hcur = hnext; hnext = tmp;
  }

  // output head (fp32; t_node aliases ein which is dead now)
  gemm_k<1><<<dim3((NN+15)/16, 1), 256, 0, stream>>>(
      hcur, 64, emb_o_w1, 64, emb_o_b1, t_node, 64, 0, NN, 64, 64);
  gemm_k<0><<<dim3((NN+15)/16, 1), 256, 0, stream>>>(
      t_node, 64, emb_o_w2, 64, emb_o_b2, hnext, 64, 0, NN, 64, 64);
  segy_k<<<(NN*64)/256, 256, 0, stream>>>(hnext, segs, y);
  gemm_k<1><<<dim3((NSEG+15)/16, 1), 256, 0, stream>>>(
      y, 64, head_w1, 64, head_b1, t2, 64, 0, NSEG, 64, 64);
  headf_k<<<1, 128, 0, stream>>>(t2, head_w2, head_b2, out);
}

// Round 4
// 1387.540 us; speedup vs baseline: 5.1442x; 1.0737x over previous
//
#include <hip/hip_runtime.h>
#include <hip/hip_bf16.h>

// ---- problem constants ----
constexpr int EN   = 100000;  // edges
constexpr int NN   = 10000;   // nodes
constexpr int DEPTH = 6;
constexpr int NSEG = 100;
constexpr int LP   = 40;      // padded LDS row stride (u16) — bank step 20, 2-way max

typedef unsigned short u16;
typedef __bf16 bf16x8 __attribute__((ext_vector_type(8)));
typedef float  f32x4  __attribute__((ext_vector_type(4)));

__device__ inline float wred_max(float v){
#pragma unroll
  for (int o = 32; o > 0; o >>= 1) v = fmaxf(v, __shfl_xor(v, o, 64));
  return v;
}
__device__ inline float wred_sum(float v){
#pragma unroll
  for (int o = 32; o > 0; o >>= 1) v += __shfl_xor(v, o, 64);
  return v;
}
__device__ inline float siluf(float x){ return x / (1.f + __expf(-x)); }
__device__ inline u16 f2bf(float x){
  __hip_bfloat16 h = __float2bfloat16(x);
  return *reinterpret_cast<u16*>(&h);
}
__device__ inline float bf2f(u16 u){
  union { float f; unsigned int ui; } v; v.ui = ((unsigned int)u) << 16; return v.f;
}

// ---- dst histogram ----
__global__ __launch_bounds__(256) void count_k(const int* __restrict__ edges,
                                               int* __restrict__ counts){
  int e = blockIdx.x * 256 + threadIdx.x;
  if (e >= EN) return;
  atomicAdd(&counts[edges[2*e]], 1);
}

// ---- exclusive scan of counts -> offsets (single block) ----
__global__ __launch_bounds__(256) void scan_k(const int* __restrict__ counts,
                                              int* __restrict__ offs){
  __shared__ int part[256];
  const int CH = (NN + 255) / 256;
  int t = threadIdx.x;
  int s = 0;
  for (int j = 0; j < CH; ++j){ int idx = t*CH + j; if (idx < NN) s += counts[idx]; }
  part[t] = s;
  __syncthreads();
  if (t == 0){
    int run = 0;
    for (int i = 0; i < 256; ++i){ int v = part[i]; part[i] = run; run += v; }
    offs[NN] = run;
  }
  __syncthreads();
  int run = part[t];
  for (int j = 0; j < CH; ++j){
    int idx = t*CH + j;
    if (idx < NN){ offs[idx] = run; run += counts[idx]; }
  }
}

// ---- geometry + scatter into CSR (dst-sorted) order ----
__global__ __launch_bounds__(256) void geoscat_k(const int* __restrict__ edges,
                                                 const float* __restrict__ x,
                                                 const int* __restrict__ offs,
                                                 int* __restrict__ cursor,
                                                 int* __restrict__ edge_s,
                                                 float* __restrict__ dS,
                                                 float* __restrict__ dirsS,
                                                 float* __restrict__ rbfS){
  int e = blockIdx.x * 256 + threadIdx.x;
  if (e >= EN) return;
  int dst = edges[2*e], src = edges[2*e+1];
  float dx = x[dst*3+0] - x[src*3+0];
  float dy = x[dst*3+1] - x[src*3+1];
  float dz = x[dst*3+2] - x[src*3+2];
  float dd = sqrtf(dx*dx + dy*dy + dz*dz + 1e-10f);
  float inv = 1.f / (dd + 1e-5f);
  int pos = offs[dst] + atomicAdd(&cursor[dst], 1);
  edge_s[2*pos]   = dst;
  edge_s[2*pos+1] = src;
  dS[pos]   = dd;
  rbfS[pos] = __expf(-dd);
  dirsS[3*pos+0] = dx*inv; dirsS[3*pos+1] = dy*inv; dirsS[3*pos+2] = dz*inv;
}

// ---- once per call: ein[p][178]=d (bf16), ein[p][179:192]=0 ----
__global__ __launch_bounds__(256) void eind_k(const float* __restrict__ dS,
                                              u16* __restrict__ ein){
  int gid = blockIdx.x * 256 + threadIdx.x;
  int e = gid >> 4, j = gid & 15;
  if (e >= EN || j >= 14) return;
  ein[(size_t)e*192 + 178 + j] = (j == 0) ? f2bf(dS[e]) : (u16)0;
}

// ---- h (fp32) -> hbf (bf16 cache) + node_in[:,0:64] ----
__global__ __launch_bounds__(256) void h2b_k(const float* __restrict__ h,
                                             u16* __restrict__ hbf,
                                             u16* __restrict__ node_in){
  int gid = blockIdx.x * 256 + threadIdx.x;
  if (gid >= NN*64) return;
  int n = gid >> 6, ch = gid & 63;
  u16 b = f2bf(h[gid]);
  hbf[gid] = b;
  node_in[(size_t)n*384 + ch] = b;
}

// ---- build edge input (bf16): ein[p][0:128] = concat(hbf[dst], hbf[src]) ----
__global__ __launch_bounds__(256) void build_ein_k(const int* __restrict__ edge_s,
                                                   const u16* __restrict__ hbf,
                                                   u16* __restrict__ ein){
  int gid = blockIdx.x * 256 + threadIdx.x;
  int e = gid >> 4, j = gid & 15;
  if (e >= EN) return;
  int node = (j < 8) ? edge_s[2*e] : edge_s[2*e+1];
  int c8 = (j & 7) * 8;
  uint4 v = *reinterpret_cast<const uint4*>(hbf + (size_t)node*64 + c8);
  *reinterpret_cast<uint4*>(ein + (size_t)e*192 + j*8) = v;
}

// ---- generic weight convert+transpose: dst[l][n][k] = bf16(src[l][k][n]) ----
__global__ void convw_k(const float* __restrict__ src, int K, int N, size_t sStride,
                        u16* __restrict__ dst, int Kpad, int Npad, size_t dStride){
  int idx = blockIdx.x * 256 + threadIdx.x;
  if (idx >= Npad*Kpad) return;
  int n = idx / Kpad, k = idx - n*Kpad;
  float v = (k < K && n < N) ? src[blockIdx.y*sStride + (size_t)k*N + n] : 0.f;
  dst[blockIdx.y*dStride + idx] = f2bf(v);
}

// ---- bf16 MFMA GEMM, 128-row M-tile, CT*16 N-tile, BK=32, 4 waves, MT=2 ----
// EPI: 1=silu bf16out, 2=tanh bf16out, 3=rbf bf16out, 4=resid+silu fp32out, 6=bias bf16out
// AMODE: 0 = A[m][k] bf16; 1 = A is he[m][64], value = he[m][k>>2]*att[m][k&3]
template<int EPI, int CT, int AMODE>
__global__ __launch_bounds__(256) void bgemm_k(const u16* __restrict__ A, int lda,
                                               const u16* __restrict__ Wt, int ldw,
                                               const float* __restrict__ bias,
                                               float* __restrict__ outf,
                                               u16* __restrict__ outb,
                                               int ldo, int ocol,
                                               int M, int Nout, int K,
                                               const float* __restrict__ e0,
                                               const float* __restrict__ e1,
                                               const float* __restrict__ e2,
                                               const float* __restrict__ attp){
  __shared__ u16 A_s[128*LP];
  __shared__ u16 B_s[CT*16*LP];
  const int tid  = threadIdx.x;
  const int lane = tid & 63;
  const int wave = tid >> 6;
  const int m0   = blockIdx.x * 128;
  const int n0   = blockIdx.y * (CT*16);
  const int l15  = lane & 15;
  const int kq   = (lane >> 4) * 8;

  // A staging: thread covers row srow, cols skh..skh+15 of the 32-col K-slab
  const int srow = tid >> 1;
  const int skh  = (tid & 1) * 16;
  const int arow = min(m0 + srow, M - 1);
  const u16* aptr = nullptr;
  const u16* heptr = nullptr;
  float4 av;
  if (AMODE == 0){
    aptr = A + (size_t)arow * lda + skh;
  } else {
    heptr = A + (size_t)arow * 64 + (skh >> 2);
    av = *reinterpret_cast<const float4*>(attp + (size_t)arow * 4);
  }
  // B staging: CT/4 uint4 chunks per thread
  int brow[CT/4], bcol[CT/4];
#pragma unroll
  for (int i = 0; i < CT/4; ++i){
    int idx = tid + i*256;
    brow[i] = idx >> 2;
    bcol[i] = (idx & 3) * 8;
  }

  f32x4 acc0[CT], acc1[CT];
#pragma unroll
  for (int c = 0; c < CT; ++c){
    acc0[c] = (f32x4){0.f,0.f,0.f,0.f};
    acc1[c] = (f32x4){0.f,0.f,0.f,0.f};
  }

  for (int kc = 0; kc < K; kc += 32){
    if (AMODE == 0){
      uint4 a0 = *reinterpret_cast<const uint4*>(aptr + kc);
      uint4 a1 = *reinterpret_cast<const uint4*>(aptr + kc + 8);
      *reinterpret_cast<uint4*>(A_s + srow*LP + skh)     = a0;
      *reinterpret_cast<uint4*>(A_s + srow*LP + skh + 8) = a1;
    } else {
      ushort4 hq = *reinterpret_cast<const ushort4*>(heptr + (kc >> 2));
      u16 o[16];
      float hv0 = bf2f(hq.x), hv1 = bf2f(hq.y), hv2 = bf2f(hq.z), hv3 = bf2f(hq.w);
#pragma unroll
      for (int hd = 0; hd < 4; ++hd){
        float a = (hd==0)?av.x:(hd==1)?av.y:(hd==2)?av.z:av.w;
        o[0*4+hd] = f2bf(hv0*a); o[1*4+hd] = f2bf(hv1*a);
        o[2*4+hd] = f2bf(hv2*a); o[3*4+hd] = f2bf(hv3*a);
      }
      *reinterpret_cast<uint4*>(A_s + srow*LP + skh)     = *reinterpret_cast<uint4*>(o);
      *reinterpret_cast<uint4*>(A_s + srow*LP + skh + 8) = *reinterpret_cast<uint4*>(o+8);
    }
#pragma unroll
    for (int i = 0; i < CT/4; ++i){
      *reinterpret_cast<uint4*>(B_s + brow[i]*LP + bcol[i]) =
          *reinterpret_cast<const uint4*>(Wt + (size_t)(n0 + brow[i])*ldw + kc + bcol[i]);
    }
    __syncthreads();
    bf16x8 af0 = *reinterpret_cast<const bf16x8*>(A_s + (wave*16 + l15)*LP + kq);
    bf16x8 af1 = *reinterpret_cast<const bf16x8*>(A_s + (64 + wave*16 + l15)*LP + kq);
#pragma unroll
    for (int c = 0; c < CT; ++c){
      bf16x8 bf = *reinterpret_cast<const bf16x8*>(B_s + (c*16 + l15)*LP + kq);
      acc0[c] = __builtin_amdgcn_mfma_f32_16x16x32_bf16(af0, bf, acc0[c], 0, 0, 0);
      acc1[c] = __builtin_amdgcn_mfma_f32_16x16x32_bf16(af1, bf, acc1[c], 0, 0, 0);
    }
    __syncthreads();
  }

  // C/D layout: col = lane&15, row = (lane>>4)*4 + r
#pragma unroll
  for (int h = 0; h < 2; ++h){
    const int rbase = m0 + h*64 + wave*16 + ((lane >> 4) << 2);
#pragma unroll
    for (int c = 0; c < CT; ++c){
      int n = n0 + c*16 + l15;
      if (n >= Nout) continue;
      float b = bias ? bias[n] : 0.f;
#pragma unroll
      for (int r = 0; r < 4; ++r){
        int m = rbase + r;
        if (m >= M) continue;
        float a = (h == 0) ? acc0[c][r] : acc1[c][r];
        if (EPI == 1){
          outb[(size_t)m*ldo + ocol + n] = f2bf(siluf(a + b));
        } else if (EPI == 2){
          outb[(size_t)m*ldo + ocol + n] = f2bf(tanhf(a));
        } else if (EPI == 3){
          float df = e0[m] - e1[n];
          outb[(size_t)m*ldo + ocol + n] = f2bf(__expf(-e2[n]*df*df) * (a + b));
        } else if (EPI == 4){
          outf[(size_t)m*ldo + ocol + n] = e0[(size_t)m*64 + n] + siluf(a + b);
        } else {
          outb[(size_t)m*ldo + ocol + n] = f2bf(a + b);
        }
      }
    }
  }
}

// ---- generic tiled fp32 GEMM (small cases) ----
template<int EPI>
__global__ __launch_bounds__(256) void gemm_k(const float* __restrict__ A, int lda,
                                              const float* __restrict__ W, int ldw,
                                              const float* __restrict__ bias,
                                              float* __restrict__ out, int ldo, int ocol,
                                              int M, int N, int K){
  __shared__ float w_s[128*64];
  const int tid  = threadIdx.x;
  const int nl   = tid & 63;
  const int rg   = tid >> 6;
  const int col0 = blockIdx.y * 64;
  const int m0   = blockIdx.x * 16 + rg * 4;
  float acc[4] = {0.f, 0.f, 0.f, 0.f};
  const float* ar[4];
#pragma unroll
  for (int r = 0; r < 4; ++r){
    int mr = min(m0 + r, M - 1);
    ar[r] = A + (size_t)mr * lda;
  }
  for (int kc = 0; kc < K; kc += 128){
    int kn = min(128, K - kc);
    for (int idx = tid; idx < 128*64; idx += 256){
      int kk = idx >> 6, nn = idx & 63;
      int gn = col0 + nn;
      w_s[idx] = (kk < kn && gn < N) ? W[(size_t)(kc+kk)*ldw + gn] : 0.f;
    }
    __syncthreads();
    for (int k = 0; k < kn; ++k){
      float wv = w_s[k*64 + nl];
#pragma unroll
      for (int r = 0; r < 4; ++r) acc[r] = fmaf(ar[r][kc + k], wv, acc[r]);
    }
    __syncthreads();
  }
  int n = col0 + nl;
  if (n >= N) return;
  float b = bias ? bias[n] : 0.f;
#pragma unroll
  for (int r = 0; r < 4; ++r){
    int m = m0 + r;
    if (m >= M) break;
    float a = acc[r] + b;
    out[(size_t)m*ldo + ocol + n] = (EPI == 1) ? siluf(a) : a;
  }
}

// ---- sem head logits + celu(alpha=2), he in bf16 (sorted order) ----
__global__ __launch_bounds__(256) void sem_k(const u16* __restrict__ he,
                                             const float* __restrict__ sw,
                                             const float* __restrict__ sb,
                                             float* __restrict__ logit){
  __shared__ float tile[64*65];
  int e0 = blockIdx.x * 64;
  for (int idx = threadIdx.x; idx < 64*16; idx += 256){
    int r = idx >> 4, c4 = (idx & 15) * 4;
    int e = e0 + r;
    ushort4 u = (e < EN) ? *reinterpret_cast<const ushort4*>(he + (size_t)e*64 + c4)
                         : (ushort4){0,0,0,0};
    tile[r*65 + c4+0] = bf2f(u.x);
    tile[r*65 + c4+1] = bf2f(u.y);
    tile[r*65 + c4+2] = bf2f(u.z);
    tile[r*65 + c4+3] = bf2f(u.w);
  }
  __syncthreads();
  int er = threadIdx.x >> 2, hd = threadIdx.x & 3;
  int e = e0 + er;
  float acc = sb[hd];
#pragma unroll 8
  for (int k = 0; k < 64; ++k) acc = fmaf(tile[er*65 + k], sw[k*4 + hd], acc);
  float v = acc > 0.f ? acc : 2.f*(__expf(0.5f*acc) - 1.f);
  if (e < EN) logit[(size_t)e*4 + hd] = v;
}

// ---- per-node attention over contiguous CSR segment ----
__global__ __launch_bounds__(256) void att_k(const int* __restrict__ offs,
                                             const float* __restrict__ dS,
                                             const float* __restrict__ logit,
                                             float* __restrict__ att){
  int lane = threadIdx.x & 63;
  int node = (blockIdx.x * 256 + threadIdx.x) >> 6;
  if (node >= NN) return;
  int s0 = offs[node];
  int cnt = offs[node+1] - s0;
  if (cnt <= 0) return;
  const float NEG = -1e30f;
  if (cnt <= 64){
    bool act = lane < cnt;
    int p = s0 + (act ? lane : 0);
    float dd = dS[p];
    float4 lg = *reinterpret_cast<const float4*>(logit + 4*(size_t)p);
    float me  = wred_max(act ? -dd  : NEG);
    float ms0 = wred_max(act ? lg.x : NEG);
    float ms1 = wred_max(act ? lg.y : NEG);
    float ms2 = wred_max(act ? lg.z : NEG);
    float ms3 = wred_max(act ? lg.w : NEG);
    float ee  = act ? __expf(-dd - me)  : 0.f;
    float v0  = act ? __expf(lg.x - ms0) : 0.f;
    float v1  = act ? __expf(lg.y - ms1) : 0.f;
    float v2  = act ? __expf(lg.z - ms2) : 0.f;
    float v3  = act ? __expf(lg.w - ms3) : 0.f;
    float ise = 1.f / wred_sum(ee);
    float is0 = 1.f / wred_sum(v0);
    float is1 = 1.f / wred_sum(v1);
    float is2 = 1.f / wred_sum(v2);
    float is3 = 1.f / wred_sum(v3);
    float ae = ee * ise;
    float a0 = ae * v0 * is0, a1 = ae * v1 * is1;
    float a2 = ae * v2 * is2, a3 = ae * v3 * is3;
    float iz0 = 1.f / wred_sum(a0), iz1 = 1.f / wred_sum(a1);
    float iz2 = 1.f / wred_sum(a2), iz3 = 1.f / wred_sum(a3);
    if (act){
      float4 o; o.x = a0*iz0; o.y = a1*iz1; o.z = a2*iz2; o.w = a3*iz3;
      *reinterpret_cast<float4*>(att + 4*(size_t)p) = o;
    }
    return;
  }
  // general path
  float me = NEG, ms0 = NEG, ms1 = NEG, ms2 = NEG, ms3 = NEG;
  for (int j = lane; j < cnt; j += 64){
    int p = s0 + j;
    float dd = dS[p];
    me = fmaxf(me, -dd);
    float4 lg = *reinterpret_cast<const float4*>(logit + 4*(size_t)p);
    ms0 = fmaxf(ms0, lg.x); ms1 = fmaxf(ms1, lg.y);
    ms2 = fmaxf(ms2, lg.z); ms3 = fmaxf(ms3, lg.w);
  }
  me = wred_max(me); ms0 = wred_max(ms0); ms1 = wred_max(ms1);
  ms2 = wred_max(ms2); ms3 = wred_max(ms3);
  float se = 0.f, ss0 = 0.f, ss1 = 0.f, ss2 = 0.f, ss3 = 0.f;
  for (int j = lane; j < cnt; j += 64){
    int p = s0 + j;
    float dd = dS[p];
    float4 lg = *reinterpret_cast<const float4*>(logit + 4*(size_t)p);
    se  += __expf(-dd - me);
    ss0 += __expf(lg.x - ms0); ss1 += __expf(lg.y - ms1);
    ss2 += __expf(lg.z - ms2); ss3 += __expf(lg.w - ms3);
  }
  se = wred_sum(se); ss0 = wred_sum(ss0); ss1 = wred_sum(ss1);
  ss2 = wred_sum(ss2); ss3 = wred_sum(ss3);
  float ise = 1.f/se, is0 = 1.f/ss0, is1 = 1.f/ss1, is2 = 1.f/ss2, is3 = 1.f/ss3;
  float z0 = 0.f, z1 = 0.f, z2 = 0.f, z3 = 0.f;
  for (int j = lane; j < cnt; j += 64){
    int p = s0 + j;
    float dd = dS[p];
    float4 lg = *reinterpret_cast<const float4*>(logit + 4*(size_t)p);
    float ae = __expf(-dd - me) * ise;
    z0 += ae * __expf(lg.x - ms0) * is0;
    z1 += ae * __expf(lg.y - ms1) * is1;
    z2 += ae * __expf(lg.z - ms2) * is2;
    z3 += ae * __expf(lg.w - ms3) * is3;
  }
  z0 = wred_sum(z0); z1 = wred_sum(z1); z2 = wred_sum(z2); z3 = wred_sum(z3);
  float iz0 = 1.f/z0, iz1 = 1.f/z1, iz2 = 1.f/z2, iz3 = 1.f/z3;
  for (int j = lane; j < cnt; j += 64){
    int p = s0 + j;
    float dd = dS[p];
    float4 lg = *reinterpret_cast<const float4*>(logit + 4*(size_t)p);
    float ae = __expf(-dd - me) * ise;
    float4 o;
    o.x = ae * __expf(lg.x - ms0) * is0 * iz0;
    o.y = ae * __expf(lg.y - ms1) * is1 * iz1;
    o.z = ae * __expf(lg.z - ms2) * is2 * iz2;
    o.w = ae * __expf(lg.w - ms3) * is3 * iz3;
    *reinterpret_cast<float4*>(att + 4*(size_t)p) = o;
  }
}

// ---- per-node aggregate (contiguous CSR): cnorm = |sum coef*dirs|^2, h_agg = sum he*att ----
__global__ __launch_bounds__(256) void agg_k(const int* __restrict__ offs,
                                             const u16* __restrict__ coef,
                                             const u16* __restrict__ he,
                                             const float* __restrict__ att,
                                             const float* __restrict__ dirsS,
                                             u16* __restrict__ cnorm,
                                             u16* __restrict__ node_in){
  int node = blockIdx.x;
  int c = threadIdx.x;
  int s0 = offs[node], s1 = offs[node+1];
  int q = c >> 2, hd = c & 3;
  float cs0 = 0.f, cs1 = 0.f, cs2 = 0.f, ha = 0.f;
  for (int p = s0; p < s1; ++p){
    float co = bf2f(coef[(size_t)p*256 + c]);
    float hv = bf2f(he[(size_t)p*64 + q]);
    float av = att[(size_t)p*4 + hd];
    float d0 = dirsS[3*(size_t)p], d1 = dirsS[3*(size_t)p+1], d2 = dirsS[3*(size_t)p+2];
    cs0 = fmaf(co, d0, cs0); cs1 = fmaf(co, d1, cs1); cs2 = fmaf(co, d2, cs2);
    ha = fmaf(hv, av, ha);
  }
  cnorm[(size_t)node*256 + c] = f2bf(cs0*cs0 + cs1*cs1 + cs2*cs2);
  node_in[(size_t)node*384 + 64 + c] = f2bf(ha);
}

// ---- graph pooling ----
__global__ __launch_bounds__(256) void segy_k(const float* __restrict__ hf,
                                              const int* __restrict__ seg,
                                              float* __restrict__ y){
  int gid = blockIdx.x * 256 + threadIdx.x;
  if (gid >= NN*64) return;
  int n = gid >> 6, ch = gid & 63;
  atomicAdd(&y[seg[n]*64 + ch], hf[gid]);
}

// ---- final head ----
__global__ void headf_k(const float* __restrict__ t2,
                        const float* __restrict__ w2,
                        const float* __restrict__ b2,
                        float* __restrict__ out){
  int s = threadIdx.x;
  if (s >= NSEG) return;
  float acc = b2[0];
  for (int k = 0; k < 64; ++k) acc = fmaf(t2[s*64 + k], w2[k], acc);
  out[s] = acc;
}

extern "C" void kernel_launch(void* const* d_in, const int* in_sizes, int n_in,
                              void* d_out, int out_size, void* d_ws, size_t ws_size,
                              hipStream_t stream) {
  (void)in_sizes; (void)n_in; (void)out_size; (void)ws_size;
  const float* in_i       = (const float*)d_in[0];
  const float* in_x       = (const float*)d_in[1];
  const float* emb_in_w   = (const float*)d_in[2];
  const float* emb_in_b   = (const float*)d_in[3];
  const float* edge_in_w  = (const float*)d_in[4];
  const float* edge_in_b  = (const float*)d_in[5];
  const float* rbf_means  = (const float*)d_in[6];
  const float* rbf_betas  = (const float*)d_in[7];
  const float* edge_o_w1  = (const float*)d_in[8];
  const float* edge_o_b1  = (const float*)d_in[9];
  const float* edge_o_w2  = (const float*)d_in[10];
  const float* edge_o_b2  = (const float*)d_in[11];
  const float* sem_w      = (const float*)d_in[12];
  const float* sem_b      = (const float*)d_in[13];
  const float* xmix_w     = (const float*)d_in[14];
  const float* pn_w1      = (const float*)d_in[15];
  const float* pn_b1      = (const float*)d_in[16];
  const float* pn_w2      = (const float*)d_in[17];
  const float* pn_b2      = (const float*)d_in[18];
  const float* node_w1    = (const float*)d_in[19];
  const float* node_b1    = (const float*)d_in[20];
  const float* node_w2    = (const float*)d_in[21];
  const float* node_b2    = (const float*)d_in[22];
  const float* emb_o_w1   = (const float*)d_in[23];
  const float* emb_o_b1   = (const float*)d_in[24];
  const float* emb_o_w2   = (const float*)d_in[25];
  const float* emb_o_b2   = (const float*)d_in[26];
  const float* head_w1    = (const float*)d_in[27];
  const float* head_b1    = (const float*)d_in[28];
  const float* head_w2    = (const float*)d_in[29];
  const float* head_b2    = (const float*)d_in[30];
  const int*   edges      = (const int*)d_in[31];
  const int*   segs       = (const int*)d_in[32];
  float* out = (float*)d_out;

  // workspace carve-up (256B aligned)
  char* base = (char*)d_ws;
  size_t off = 0;
  auto alloc = [&](size_t bytes) -> void* {
    void* p = base + off;
    off += (bytes + 255) & ~(size_t)255;
    return p;
  };
  float* dS     = (float*)alloc((size_t)EN*4);
  float* dirsS  = (float*)alloc((size_t)EN*3*4);
  float* rbfS   = (float*)alloc((size_t)EN*4);
  int*   edge_s = (int*)alloc((size_t)EN*2*4);
  float* hA     = (float*)alloc((size_t)NN*64*4);
  float* hB     = (float*)alloc((size_t)NN*64*4);
  u16*   ein    = (u16*)alloc((size_t)EN*192*2);
  u16*   t_edge = (u16*)alloc((size_t)EN*64*2);
  u16*   he     = (u16*)alloc((size_t)EN*64*2);
  u16*   coef   = (u16*)alloc((size_t)EN*256*2);
  float* logit  = (float*)alloc((size_t)EN*4*4);
  float* att    = (float*)alloc((size_t)EN*4*4);
  u16*   hbf    = (u16*)alloc((size_t)NN*64*2);
  u16*   node_in= (u16*)alloc((size_t)NN*384*2);
  u16*   cnorm  = (u16*)alloc((size_t)NN*256*2);
  u16*   pn_t   = (u16*)alloc((size_t)NN*64*2);
  u16*   tnb    = (u16*)alloc((size_t)NN*64*2);
  float* y      = (float*)alloc((size_t)NSEG*64*4);
  float* t2     = (float*)alloc((size_t)NSEG*64*4);
  u16* winb  = (u16*)alloc((size_t)DEPTH*64*128*2);
  u16* w1b   = (u16*)alloc((size_t)DEPTH*64*192*2);
  u16* w2b   = (u16*)alloc((size_t)DEPTH*64*64*2);
  u16* xwb   = (u16*)alloc((size_t)DEPTH*256*256*2);
  u16* pw1b  = (u16*)alloc((size_t)DEPTH*64*256*2);
  u16* pw2b  = (u16*)alloc((size_t)DEPTH*64*64*2);
  u16* nw1b  = (u16*)alloc((size_t)DEPTH*64*384*2);
  u16* nw2b  = (u16*)alloc((size_t)DEPTH*64*64*2);
  int* counts   = (int*)alloc((size_t)NN*4);
  int* cursor   = (int*)alloc((size_t)NN*4);
  int* offs     = (int*)alloc((size_t)(NN+1)*4);
  // fp32 scratch for final head, aliased over ein (dead by then)
  float* t_node = (float*)ein;

  hipMemsetAsync(counts, 0, (size_t)NN*4, stream);
  hipMemsetAsync(cursor, 0, (size_t)NN*4, stream);
  hipMemsetAsync(y, 0, (size_t)NSEG*64*4, stream);

  count_k<<<(EN+255)/256, 256, 0, stream>>>(edges, counts);
  scan_k<<<1, 256, 0, stream>>>(counts, offs);
  geoscat_k<<<(EN+255)/256, 256, 0, stream>>>(edges, in_x, offs, cursor,
                                              edge_s, dS, dirsS, rbfS);
  eind_k<<<(EN*16+255)/256, 256, 0, stream>>>(dS, ein);

  // weight conversions (once per call)
  convw_k<<<dim3(32,  DEPTH), 256, 0, stream>>>(edge_in_w, 128, 50, (size_t)128*50, winb, 128, 64, (size_t)64*128);
  convw_k<<<dim3(48,  DEPTH), 256, 0, stream>>>(edge_o_w1, 179, 64, (size_t)179*64, w1b,  192, 64, (size_t)64*192);
  convw_k<<<dim3(16,  DEPTH), 256, 0, stream>>>(edge_o_w2,  64, 64, (size_t)64*64,  w2b,   64, 64, (size_t)64*64);
  convw_k<<<dim3(256, DEPTH), 256, 0, stream>>>(xmix_w,    256,256, (size_t)256*256,xwb,  256,256, (size_t)256*256);
  convw_k<<<dim3(64,  DEPTH), 256, 0, stream>>>(pn_w1,     256, 64, (size_t)256*64, pw1b, 256, 64, (size_t)64*256);
  convw_k<<<dim3(16,  DEPTH), 256, 0, stream>>>(pn_w2,      64, 64, (size_t)64*64,  pw2b,  64, 64, (size_t)64*64);
  convw_k<<<dim3(96,  DEPTH), 256, 0, stream>>>(node_w1,   384, 64, (size_t)384*64, nw1b, 384, 64, (size_t)64*384);
  convw_k<<<dim3(16,  DEPTH), 256, 0, stream>>>(node_w2,    64, 64, (size_t)64*64,  nw2b,  64, 64, (size_t)64*64);

  // h = i @ emb_in_w + b   (fp32, K=16)
  gemm_k<0><<<dim3((NN+15)/16, 1), 256, 0, stream>>>(
      in_i, 16, emb_in_w, 64, emb_in_b, hA, 64, 0, NN, 64, 16);

  const int EB  = (EN + 63) / 64;     // sem blocks
  const int EB2 = (EN + 127) / 128;   // 782
  const int NB2 = (NN + 127) / 128;   // 79

  float* hcur = hA;
  float* hnext = hB;
  for (int l = 0; l < DEPTH; ++l){
    const float* bin  = edge_in_b + (size_t)l*50;
    const float* mean = rbf_means + (size_t)l*50;
    const float* beta = rbf_betas + (size_t)l*50;
    const float* b1   = edge_o_b1 + (size_t)l*64;
    const float* b2   = edge_o_b2 + (size_t)l*64;
    const float* sw   = sem_w + (size_t)l*64*4;
    const float* sb   = sem_b + (size_t)l*4;
    const float* pb1  = pn_b1 + (size_t)l*64;
    const float* pb2  = pn_b2 + (size_t)l*64;
    const float* nb1  = node_b1 + (size_t)l*64;
    const float* nb2  = node_b2 + (size_t)l*64;
    const u16* Winb = winb + (size_t)l*64*128;
    const u16* W1b  = w1b  + (size_t)l*64*192;
    const u16* W2b  = w2b  + (size_t)l*64*64;
    const u16* Xwb  = xwb  + (size_t)l*256*256;
    const u16* P1b  = pw1b + (size_t)l*64*256;
    const u16* P2b  = pw2b + (size_t)l*64*64;
    const u16* N1b  = nw1b + (size_t)l*64*384;
    const u16* N2b  = nw2b + (size_t)l*64*64;

    h2b_k<<<(NN*64)/256, 256, 0, stream>>>(hcur, hbf, node_in);
    build_ein_k<<<(EN*16)/256, 256, 0, stream>>>(edge_s, hbf, ein);
    // rbf*hm -> ein[:,128:178]
    bgemm_k<3,4,0><<<dim3(EB2,1), 256, 0, stream>>>(
        ein, 192, Winb, 128, bin, nullptr, ein, 192, 128, EN, 50, 128,
        rbfS, mean, beta, nullptr);
    // t = silu(ein @ W1 + b1)
    bgemm_k<1,4,0><<<dim3(EB2,1), 256, 0, stream>>>(
        ein, 192, W1b, 192, b1, nullptr, t_edge, 64, 0, EN, 64, 192,
        nullptr, nullptr, nullptr, nullptr);
    // he = t @ W2 + b2 (bf16)
    bgemm_k<6,4,0><<<dim3(EB2,1), 256, 0, stream>>>(
        t_edge, 64, W2b, 64, b2, nullptr, he, 64, 0, EN, 64, 64,
        nullptr, nullptr, nullptr, nullptr);
    sem_k<<<EB, 256, 0, stream>>>(he, sw, sb, logit);
    att_k<<<(NN+3)/4, 256, 0, stream>>>(offs, dS, logit, att);
    // coef = tanh((he x att) @ xmix)  — hea staged on the fly
    bgemm_k<2,8,1><<<dim3(EB2,2), 256, 0, stream>>>(
        he, 64, Xwb, 256, nullptr, nullptr, coef, 256, 0, EN, 256, 256,
        nullptr, nullptr, nullptr, att);
    agg_k<<<NN, 256, 0, stream>>>(offs, coef, he, att, dirsS, cnorm, node_in);
    // h_comb = silu(silu(cnorm@pn_w1+b1)@pn_w2+b2) -> node_in[:,320:384]
    bgemm_k<1,4,0><<<dim3(NB2,1), 256, 0, stream>>>(
        cnorm, 256, P1b, 256, pb1, nullptr, pn_t, 64, 0, NN, 64, 256,
        nullptr, nullptr, nullptr, nullptr);
    bgemm_k<1,4,0><<<dim3(NB2,1), 256, 0, stream>>>(
        pn_t, 64, P2b, 64, pb2, nullptr, node_in, 384, 320, NN, 64, 64,
        nullptr, nullptr, nullptr, nullptr);
    // node update
    bgemm_k<1,4,0><<<dim3(NB2,1), 256, 0, stream>>>(
        node_in, 384, N1b, 384, nb1, nullptr, tnb, 64, 0, NN, 64, 384,
        nullptr, nullptr, nullptr, nullptr);
    bgemm_k<4,4,0><<<dim3(NB2,1), 256, 0, stream>>>(
        tnb, 64, N2b, 64, nb2, hnext, nullptr, 64, 0, NN, 64, 64,
        hcur, nullptr, nullptr, nullptr);
    float* tmp = hcur; hcur = hnext; hnext = tmp;
  }

  // output head (fp32; t_node aliases ein which is dead now)
  gemm_k<1><<<dim3((NN+15)/16, 1), 256, 0, stream>>>(
      hcur, 64, emb_o_w1, 64, emb_o_b1, t_node, 64, 0, NN, 64, 64);
  gemm_k<0><<<dim3((NN+15)/16, 1), 256, 0, stream>>>(
      t_node, 64, emb_o_w2, 64, emb_o_b2, hnext, 64, 0, NN, 64, 64);
  segy_k<<<(NN*64)/256, 256, 0, stream>>>(hnext, segs, y);
  gemm_k<1><<<dim3((NSEG+15)/16, 1), 256, 0, stream>>>(
      y, 64, head_w1, 64, head_b1, t2, 64, 0, NSEG, 64, 64);
  headf_k<<<1, 128, 0, stream>>>(t2, head_w2, head_b2, out);
}

// Round 5
// 1157.631 us; speedup vs baseline: 6.1659x; 1.1986x over previous
//
#include <hip/hip_runtime.h>
#include <hip/hip_bf16.h>

// ---- problem constants ----
constexpr int EN   = 100000;  // edges
constexpr int NN   = 10000;   // nodes
constexpr int DEPTH = 6;
constexpr int NSEG = 100;
constexpr int LP   = 40;      // padded LDS row stride (u16) for bgemm/mlp2

typedef unsigned short u16;
typedef __bf16 bf16x8 __attribute__((ext_vector_type(8)));
typedef float  f32x4  __attribute__((ext_vector_type(4)));

__device__ inline float wred_max(float v){
#pragma unroll
  for (int o = 32; o > 0; o >>= 1) v = fmaxf(v, __shfl_xor(v, o, 64));
  return v;
}
__device__ inline float wred_sum(float v){
#pragma unroll
  for (int o = 32; o > 0; o >>= 1) v += __shfl_xor(v, o, 64);
  return v;
}
__device__ inline float siluf(float x){ return x / (1.f + __expf(-x)); }
__device__ inline u16 f2bf(float x){
  __hip_bfloat16 h = __float2bfloat16(x);
  return *reinterpret_cast<u16*>(&h);
}
__device__ inline float bf2f(u16 u){
  union { float f; unsigned int ui; } v; v.ui = ((unsigned int)u) << 16; return v.f;
}

// ---- dst histogram ----
__global__ __launch_bounds__(256) void count_k(const int* __restrict__ edges,
                                               int* __restrict__ counts){
  int e = blockIdx.x * 256 + threadIdx.x;
  if (e >= EN) return;
  atomicAdd(&counts[edges[2*e]], 1);
}

// ---- exclusive scan of counts -> offsets (single block) ----
__global__ __launch_bounds__(256) void scan_k(const int* __restrict__ counts,
                                              int* __restrict__ offs){
  __shared__ int part[256];
  const int CH = (NN + 255) / 256;
  int t = threadIdx.x;
  int s = 0;
  for (int j = 0; j < CH; ++j){ int idx = t*CH + j; if (idx < NN) s += counts[idx]; }
  part[t] = s;
  __syncthreads();
  if (t == 0){
    int run = 0;
    for (int i = 0; i < 256; ++i){ int v = part[i]; part[i] = run; run += v; }
    offs[NN] = run;
  }
  __syncthreads();
  int run = part[t];
  for (int j = 0; j < CH; ++j){
    int idx = t*CH + j;
    if (idx < NN){ offs[idx] = run; run += counts[idx]; }
  }
}

// ---- geometry + scatter into CSR (dst-sorted) order ----
__global__ __launch_bounds__(256) void geoscat_k(const int* __restrict__ edges,
                                                 const float* __restrict__ x,
                                                 const int* __restrict__ offs,
                                                 int* __restrict__ cursor,
                                                 int* __restrict__ edge_s,
                                                 float* __restrict__ dS,
                                                 float* __restrict__ dirsS,
                                                 float* __restrict__ rbfS){
  int e = blockIdx.x * 256 + threadIdx.x;
  if (e >= EN) return;
  int dst = edges[2*e], src = edges[2*e+1];
  float dx = x[dst*3+0] - x[src*3+0];
  float dy = x[dst*3+1] - x[src*3+1];
  float dz = x[dst*3+2] - x[src*3+2];
  float dd = sqrtf(dx*dx + dy*dy + dz*dz + 1e-10f);
  float inv = 1.f / (dd + 1e-5f);
  int pos = offs[dst] + atomicAdd(&cursor[dst], 1);
  edge_s[2*pos]   = dst;
  edge_s[2*pos+1] = src;
  dS[pos]   = dd;
  rbfS[pos] = __expf(-dd);
  dirsS[3*pos+0] = dx*inv; dirsS[3*pos+1] = dy*inv; dirsS[3*pos+2] = dz*inv;
}

// ---- h (fp32) -> hbf (bf16 cache) + node_in[:,0:64] (pre-loop only) ----
__global__ __launch_bounds__(256) void h2b_k(const float* __restrict__ h,
                                             u16* __restrict__ hbf,
                                             u16* __restrict__ node_in){
  int gid = blockIdx.x * 256 + threadIdx.x;
  if (gid >= NN*64) return;
  int n = gid >> 6, ch = gid & 63;
  u16 b = f2bf(h[gid]);
  hbf[gid] = b;
  node_in[(size_t)n*384 + ch] = b;
}

// ---- generic weight convert+transpose: dst[l][n][k] = bf16(src[l][k][n]) ----
__global__ void convw_k(const float* __restrict__ src, int K, int N, size_t sStride,
                        u16* __restrict__ dst, int Kpad, int Npad, size_t dStride){
  int idx = blockIdx.x * 256 + threadIdx.x;
  if (idx >= Npad*Kpad) return;
  int n = idx / Kpad, k = idx - n*Kpad;
  float v = (k < K && n < N) ? src[blockIdx.y*sStride + (size_t)k*N + n] : 0.f;
  dst[blockIdx.y*dStride + idx] = f2bf(v);
}

// ==== FUSED EDGE KERNEL: gather hc -> Win GEMM -> rbf -> W1 GEMM -> W2 GEMM -> sem ====
// 64-edge tile, 256 threads (4 waves). Wave w owns N-slice [16w,16w+16).
__global__ __launch_bounds__(256) void edge_fused_k(
    const int* __restrict__ edge_s,
    const u16* __restrict__ hbf,
    const float* __restrict__ rbfS,
    const float* __restrict__ dS,
    const u16* __restrict__ Winb,   // 64 x 128 (N x K)
    const float* __restrict__ bin,  // 50
    const float* __restrict__ mean, // 50
    const float* __restrict__ beta, // 50
    const u16* __restrict__ W1b,    // 64 x 192
    const float* __restrict__ b1,   // 64
    const u16* __restrict__ W2b,    // 64 x 64
    const float* __restrict__ b2,   // 64
    const float* __restrict__ sw,   // 64 x 4
    const float* __restrict__ sb,   // 4
    u16* __restrict__ he,
    float* __restrict__ logit){
  __shared__ u16 HC[64*132];   // hc tile
  __shared__ u16 WA[64*132];   // Win^T then W1a^T
  __shared__ u16 T2[64*72];    // rbf*hm | d | 0   (later: he for sem)
  __shared__ u16 WB[64*72];    // W1b^T then W2^T
  __shared__ u16 HE1[64*72];   // silu(edge hidden)
  const int tid = threadIdx.x, lane = tid & 63, wv = tid >> 6;
  const int l15 = lane & 15, kq = (lane >> 4) * 8;
  const int rsub = (lane >> 4) << 2;   // C/D row base within subtile
  const int e0 = blockIdx.x * 64;

  // P0: gather HC (hc = [h[dst], h[src]]) + stage Win^T
#pragma unroll
  for (int i = 0; i < 4; ++i){
    int idx = tid + i*256;            // 0..1023
    int row = idx >> 4, c = idx & 15;
    int e = min(e0 + row, EN - 1);
    int node = (c < 8) ? edge_s[2*e] : edge_s[2*e+1];
    *reinterpret_cast<uint4*>(HC + row*132 + c*8) =
        *reinterpret_cast<const uint4*>(hbf + (size_t)node*64 + (c & 7)*8);
    *reinterpret_cast<uint4*>(WA + row*132 + c*8) =
        *reinterpret_cast<const uint4*>(Winb + row*128 + c*8);
  }
  __syncthreads();

  // P1: hm = hc @ Win ; epilogue rbf-scale -> T2
  f32x4 acc[4];
#pragma unroll
  for (int mt = 0; mt < 4; ++mt) acc[mt] = (f32x4){0.f,0.f,0.f,0.f};
#pragma unroll
  for (int kc = 0; kc < 128; kc += 32){
    bf16x8 bf = *reinterpret_cast<const bf16x8*>(WA + (wv*16 + l15)*132 + kc + kq);
#pragma unroll
    for (int mt = 0; mt < 4; ++mt){
      bf16x8 af = *reinterpret_cast<const bf16x8*>(HC + (mt*16 + l15)*132 + kc + kq);
      acc[mt] = __builtin_amdgcn_mfma_f32_16x16x32_bf16(af, bf, acc[mt], 0, 0, 0);
    }
  }
  {
    int n = wv*16 + l15;
    float bi = 0.f, mn = 0.f, bt = 0.f;
    if (n < 50){ bi = bin[n]; mn = mean[n]; bt = beta[n]; }
#pragma unroll
    for (int mt = 0; mt < 4; ++mt){
#pragma unroll
      for (int r = 0; r < 4; ++r){
        int row = mt*16 + rsub + r;
        int e = min(e0 + row, EN - 1);
        float v;
        if (n < 50){ float df = rbfS[e] - mn; v = __expf(-bt*df*df) * (acc[mt][r] + bi); }
        else if (n == 50) v = dS[e];
        else v = 0.f;
        T2[row*72 + n] = f2bf(v);
      }
    }
  }
  __syncthreads();

  // P2: stage W1a^T (K 0..127) -> WA, W1b-part^T (K 128..191) -> WB
#pragma unroll
  for (int i = 0; i < 4; ++i){
    int idx = tid + i*256;
    int row = idx >> 4, c = idx & 15;
    *reinterpret_cast<uint4*>(WA + row*132 + c*8) =
        *reinterpret_cast<const uint4*>(W1b + row*192 + c*8);
  }
#pragma unroll
  for (int i = 0; i < 2; ++i){
    int idx = tid + i*256;
    int row = idx >> 3, cc = (idx & 7)*8;
    *reinterpret_cast<uint4*>(WB + row*72 + cc) =
        *reinterpret_cast<const uint4*>(W1b + row*192 + 128 + cc);
  }
  __syncthreads();

  // P3: he1 = silu(hc@W1a + T2@W1b + b1)
#pragma unroll
  for (int mt = 0; mt < 4; ++mt) acc[mt] = (f32x4){0.f,0.f,0.f,0.f};
#pragma unroll
  for (int kc = 0; kc < 128; kc += 32){
    bf16x8 bf = *reinterpret_cast<const bf16x8*>(WA + (wv*16 + l15)*132 + kc + kq);
#pragma unroll
    for (int mt = 0; mt < 4; ++mt){
      bf16x8 af = *reinterpret_cast<const bf16x8*>(HC + (mt*16 + l15)*132 + kc + kq);
      acc[mt] = __builtin_amdgcn_mfma_f32_16x16x32_bf16(af, bf, acc[mt], 0, 0, 0);
    }
  }
#pragma unroll
  for (int kc = 0; kc < 64; kc += 32){
    bf16x8 bf = *reinterpret_cast<const bf16x8*>(WB + (wv*16 + l15)*72 + kc + kq);
#pragma unroll
    for (int mt = 0; mt < 4; ++mt){
      bf16x8 af = *reinterpret_cast<const bf16x8*>(T2 + (mt*16 + l15)*72 + kc + kq);
      acc[mt] = __builtin_amdgcn_mfma_f32_16x16x32_bf16(af, bf, acc[mt], 0, 0, 0);
    }
  }
  {
    int n = wv*16 + l15;
    float bb = b1[n];
#pragma unroll
    for (int mt = 0; mt < 4; ++mt){
#pragma unroll
      for (int r = 0; r < 4; ++r){
        int row = mt*16 + rsub + r;
        HE1[row*72 + n] = f2bf(siluf(acc[mt][r] + bb));
      }
    }
  }
  __syncthreads();

  // P4: stage W2^T -> WB
#pragma unroll
  for (int i = 0; i < 2; ++i){
    int idx = tid + i*256;
    int row = idx >> 3, cc = (idx & 7)*8;
    *reinterpret_cast<uint4*>(WB + row*72 + cc) =
        *reinterpret_cast<const uint4*>(W2b + row*64 + cc);
  }
  __syncthreads();

  // P5: he = he1 @ W2 + b2 -> global + T2 (for sem)
#pragma unroll
  for (int mt = 0; mt < 4; ++mt) acc[mt] = (f32x4){0.f,0.f,0.f,0.f};
#pragma unroll
  for (int kc = 0; kc < 64; kc += 32){
    bf16x8 bf = *reinterpret_cast<const bf16x8*>(WB + (wv*16 + l15)*72 + kc + kq);
#pragma unroll
    for (int mt = 0; mt < 4; ++mt){
      bf16x8 af = *reinterpret_cast<const bf16x8*>(HE1 + (mt*16 + l15)*72 + kc + kq);
      acc[mt] = __builtin_amdgcn_mfma_f32_16x16x32_bf16(af, bf, acc[mt], 0, 0, 0);
    }
  }
  {
    int n = wv*16 + l15;
    float bb = b2[n];
#pragma unroll
    for (int mt = 0; mt < 4; ++mt){
#pragma unroll
      for (int r = 0; r < 4; ++r){
        int row = mt*16 + rsub + r;
        int e = e0 + row;
        u16 hb = f2bf(acc[mt][r] + bb);
        if (e < EN) he[(size_t)e*64 + n] = hb;
        T2[row*72 + n] = hb;
      }
    }
  }
  __syncthreads();

  // P6: sem logits + celu(alpha=2)
  {
    int er = tid >> 2, hd = tid & 3;
    float a = sb[hd];
#pragma unroll 8
    for (int k = 0; k < 64; ++k)
      a = fmaf(bf2f(T2[er*72 + k]), sw[k*4 + hd], a);
    float v = a > 0.f ? a : 2.f*(__expf(0.5f*a) - 1.f);
    int e = e0 + er;
    if (e < EN) logit[(size_t)e*4 + hd] = v;
  }
}

// ==== bf16 MFMA GEMM (xmix only): 128-row M-tile, CT*16 N-tile, BK=32 ====
// EPI 2 = tanh bf16out; AMODE 1: A value = he[m][k>>2]*att[m][k&3]
template<int EPI, int CT, int AMODE>
__global__ __launch_bounds__(256) void bgemm_k(const u16* __restrict__ A, int lda,
                                               const u16* __restrict__ Wt, int ldw,
                                               const float* __restrict__ bias,
                                               float* __restrict__ outf,
                                               u16* __restrict__ outb,
                                               int ldo, int ocol,
                                               int M, int Nout, int K,
                                               const float* __restrict__ attp){
  __shared__ u16 A_s[128*LP];
  __shared__ u16 B_s[CT*16*LP];
  const int tid  = threadIdx.x;
  const int lane = tid & 63;
  const int wave = tid >> 6;
  const int m0   = blockIdx.x * 128;
  const int n0   = blockIdx.y * (CT*16);
  const int l15  = lane & 15;
  const int kq   = (lane >> 4) * 8;

  const int srow = tid >> 1;
  const int skh  = (tid & 1) * 16;
  const int arow = min(m0 + srow, M - 1);
  const u16* aptr = nullptr;
  const u16* heptr = nullptr;
  float4 av;
  if (AMODE == 0){
    aptr = A + (size_t)arow * lda + skh;
  } else {
    heptr = A + (size_t)arow * 64 + (skh >> 2);
    av = *reinterpret_cast<const float4*>(attp + (size_t)arow * 4);
  }
  int brow[CT/4], bcol[CT/4];
#pragma unroll
  for (int i = 0; i < CT/4; ++i){
    int idx = tid + i*256;
    brow[i] = idx >> 2;
    bcol[i] = (idx & 3) * 8;
  }

  f32x4 acc0[CT], acc1[CT];
#pragma unroll
  for (int c = 0; c < CT; ++c){
    acc0[c] = (f32x4){0.f,0.f,0.f,0.f};
    acc1[c] = (f32x4){0.f,0.f,0.f,0.f};
  }

  for (int kc = 0; kc < K; kc += 32){
    if (AMODE == 0){
      *reinterpret_cast<uint4*>(A_s + srow*LP + skh)     = *reinterpret_cast<const uint4*>(aptr + kc);
      *reinterpret_cast<uint4*>(A_s + srow*LP + skh + 8) = *reinterpret_cast<const uint4*>(aptr + kc + 8);
    } else {
      ushort4 hq = *reinterpret_cast<const ushort4*>(heptr + (kc >> 2));
      u16 o[16];
      float hv0 = bf2f(hq.x), hv1 = bf2f(hq.y), hv2 = bf2f(hq.z), hv3 = bf2f(hq.w);
#pragma unroll
      for (int hd = 0; hd < 4; ++hd){
        float a = (hd==0)?av.x:(hd==1)?av.y:(hd==2)?av.z:av.w;
        o[0*4+hd] = f2bf(hv0*a); o[1*4+hd] = f2bf(hv1*a);
        o[2*4+hd] = f2bf(hv2*a); o[3*4+hd] = f2bf(hv3*a);
      }
      *reinterpret_cast<uint4*>(A_s + srow*LP + skh)     = *reinterpret_cast<uint4*>(o);
      *reinterpret_cast<uint4*>(A_s + srow*LP + skh + 8) = *reinterpret_cast<uint4*>(o+8);
    }
#pragma unroll
    for (int i = 0; i < CT/4; ++i){
      *reinterpret_cast<uint4*>(B_s + brow[i]*LP + bcol[i]) =
          *reinterpret_cast<const uint4*>(Wt + (size_t)(n0 + brow[i])*ldw + kc + bcol[i]);
    }
    __syncthreads();
    bf16x8 af0 = *reinterpret_cast<const bf16x8*>(A_s + (wave*16 + l15)*LP + kq);
    bf16x8 af1 = *reinterpret_cast<const bf16x8*>(A_s + (64 + wave*16 + l15)*LP + kq);
#pragma unroll
    for (int c = 0; c < CT; ++c){
      bf16x8 bf = *reinterpret_cast<const bf16x8*>(B_s + (c*16 + l15)*LP + kq);
      acc0[c] = __builtin_amdgcn_mfma_f32_16x16x32_bf16(af0, bf, acc0[c], 0, 0, 0);
      acc1[c] = __builtin_amdgcn_mfma_f32_16x16x32_bf16(af1, bf, acc1[c], 0, 0, 0);
    }
    __syncthreads();
  }

#pragma unroll
  for (int h = 0; h < 2; ++h){
    const int rbase = m0 + h*64 + wave*16 + ((lane >> 4) << 2);
#pragma unroll
    for (int c = 0; c < CT; ++c){
      int n = n0 + c*16 + l15;
      if (n >= Nout) continue;
#pragma unroll
      for (int r = 0; r < 4; ++r){
        int m = rbase + r;
        if (m >= M) continue;
        float a = (h == 0) ? acc0[c][r] : acc1[c][r];
        outb[(size_t)m*ldo + ocol + n] = f2bf(tanhf(a));
      }
    }
  }
}

// ==== fused 2-layer node MLP: out2 = epi2( silu(A@W1+b1) @ W2 + b2 ) ====
// MODE 0: pn — node_in[:,320:384] = silu(...)
// MODE 1: node update — h' = h + silu(...); writes hout(fp32), hbf, node_in[:,0:64]
template<int MODE>
__global__ __launch_bounds__(256) void mlp2_k(const u16* __restrict__ A, int lda, int K1,
                                              const u16* __restrict__ W1t,
                                              const float* __restrict__ b1,
                                              const u16* __restrict__ W2t,
                                              const float* __restrict__ b2,
                                              int M,
                                              u16* __restrict__ node_in,
                                              const float* __restrict__ hres,
                                              float* __restrict__ hout,
                                              u16* __restrict__ hbf){
  __shared__ u16 A_s[128*LP];
  __shared__ u16 B_s[64*LP];
  __shared__ u16 T_s[128*72];
  __shared__ u16 W2_s[64*72];
  const int tid = threadIdx.x, lane = tid & 63, wave = tid >> 6;
  const int m0 = blockIdx.x * 128;
  const int l15 = lane & 15, kq = (lane >> 4)*8;
  const int rsub = (lane >> 4) << 2;
  // stage W2^T once
#pragma unroll
  for (int i = 0; i < 2; ++i){
    int idx = tid + i*256;
    int row = idx >> 3, cc = (idx & 7)*8;
    *reinterpret_cast<uint4*>(W2_s + row*72 + cc) =
        *reinterpret_cast<const uint4*>(W2t + row*64 + cc);
  }
  const int srow = tid >> 1, skh = (tid & 1)*16;
  const int arow = min(m0 + srow, M - 1);
  const u16* aptr = A + (size_t)arow*lda + skh;
  const int brow = tid >> 2, bcol = (tid & 3)*8;

  f32x4 acc0[4], acc1[4];
#pragma unroll
  for (int c = 0; c < 4; ++c){ acc0[c] = (f32x4){0,0,0,0}; acc1[c] = (f32x4){0,0,0,0}; }

  for (int kc = 0; kc < K1; kc += 32){
    *reinterpret_cast<uint4*>(A_s + srow*LP + skh)     = *reinterpret_cast<const uint4*>(aptr + kc);
    *reinterpret_cast<uint4*>(A_s + srow*LP + skh + 8) = *reinterpret_cast<const uint4*>(aptr + kc + 8);
    *reinterpret_cast<uint4*>(B_s + brow*LP + bcol) =
        *reinterpret_cast<const uint4*>(W1t + (size_t)brow*K1 + kc + bcol);
    __syncthreads();
    bf16x8 af0 = *reinterpret_cast<const bf16x8*>(A_s + (wave*16 + l15)*LP + kq);
    bf16x8 af1 = *reinterpret_cast<const bf16x8*>(A_s + (64 + wave*16 + l15)*LP + kq);
#pragma unroll
    for (int c = 0; c < 4; ++c){
      bf16x8 bf = *reinterpret_cast<const bf16x8*>(B_s + (c*16 + l15)*LP + kq);
      acc0[c] = __builtin_amdgcn_mfma_f32_16x16x32_bf16(af0, bf, acc0[c], 0, 0, 0);
      acc1[c] = __builtin_amdgcn_mfma_f32_16x16x32_bf16(af1, bf, acc1[c], 0, 0, 0);
    }
    __syncthreads();
  }
  // epi1 -> T_s
#pragma unroll
  for (int h = 0; h < 2; ++h){
#pragma unroll
    for (int c = 0; c < 4; ++c){
      int n = c*16 + l15;
      float bb = b1[n];
#pragma unroll
      for (int r = 0; r < 4; ++r){
        int rowloc = h*64 + wave*16 + rsub + r;
        float a = (h == 0) ? acc0[c][r] : acc1[c][r];
        T_s[rowloc*72 + n] = f2bf(siluf(a + bb));
      }
    }
  }
  __syncthreads();
  // GEMM2: K=64
#pragma unroll
  for (int c = 0; c < 4; ++c){ acc0[c] = (f32x4){0,0,0,0}; acc1[c] = (f32x4){0,0,0,0}; }
#pragma unroll
  for (int kc = 0; kc < 64; kc += 32){
    bf16x8 af0 = *reinterpret_cast<const bf16x8*>(T_s + (wave*16 + l15)*72 + kc + kq);
    bf16x8 af1 = *reinterpret_cast<const bf16x8*>(T_s + (64 + wave*16 + l15)*72 + kc + kq);
#pragma unroll
    for (int c = 0; c < 4; ++c){
      bf16x8 bf = *reinterpret_cast<const bf16x8*>(W2_s + (c*16 + l15)*72 + kc + kq);
      acc0[c] = __builtin_amdgcn_mfma_f32_16x16x32_bf16(af0, bf, acc0[c], 0, 0, 0);
      acc1[c] = __builtin_amdgcn_mfma_f32_16x16x32_bf16(af1, bf, acc1[c], 0, 0, 0);
    }
  }
  // epi2
#pragma unroll
  for (int h = 0; h < 2; ++h){
#pragma unroll
    for (int c = 0; c < 4; ++c){
      int n = c*16 + l15;
      float bb = b2[n];
#pragma unroll
      for (int r = 0; r < 4; ++r){
        int m = m0 + h*64 + wave*16 + rsub + r;
        if (m >= M) continue;
        float a = (h == 0) ? acc0[c][r] : acc1[c][r];
        float v = siluf(a + bb);
        if (MODE == 0){
          node_in[(size_t)m*384 + 320 + n] = f2bf(v);
        } else {
          float hn = hres[(size_t)m*64 + n] + v;
          hout[(size_t)m*64 + n] = hn;
          u16 bbf = f2bf(hn);
          hbf[(size_t)m*64 + n] = bbf;
          node_in[(size_t)m*384 + n] = bbf;
        }
      }
    }
  }
}

// ---- generic tiled fp32 GEMM (small cases) ----
template<int EPI>
__global__ __launch_bounds__(256) void gemm_k(const float* __restrict__ A, int lda,
                                              const float* __restrict__ W, int ldw,
                                              const float* __restrict__ bias,
                                              float* __restrict__ out, int ldo, int ocol,
                                              int M, int N, int K){
  __shared__ float w_s[128*64];
  const int tid  = threadIdx.x;
  const int nl   = tid & 63;
  const int rg   = tid >> 6;
  const int col0 = blockIdx.y * 64;
  const int m0   = blockIdx.x * 16 + rg * 4;
  float acc[4] = {0.f, 0.f, 0.f, 0.f};
  const float* ar[4];
#pragma unroll
  for (int r = 0; r < 4; ++r){
    int mr = min(m0 + r, M - 1);
    ar[r] = A + (size_t)mr * lda;
  }
  for (int kc = 0; kc < K; kc += 128){
    int kn = min(128, K - kc);
    for (int idx = tid; idx < 128*64; idx += 256){
      int kk = idx >> 6, nn = idx & 63;
      int gn = col0 + nn;
      w_s[idx] = (kk < kn && gn < N) ? W[(size_t)(kc+kk)*ldw + gn] : 0.f;
    }
    __syncthreads();
    for (int k = 0; k < kn; ++k){
      float wv = w_s[k*64 + nl];
#pragma unroll
      for (int r = 0; r < 4; ++r) acc[r] = fmaf(ar[r][kc + k], wv, acc[r]);
    }
    __syncthreads();
  }
  int n = col0 + nl;
  if (n >= N) return;
  float b = bias ? bias[n] : 0.f;
#pragma unroll
  for (int r = 0; r < 4; ++r){
    int m = m0 + r;
    if (m >= M) break;
    float a = acc[r] + b;
    out[(size_t)m*ldo + ocol + n] = (EPI == 1) ? siluf(a) : a;
  }
}

// ---- per-node attention over contiguous CSR segment ----
__global__ __launch_bounds__(256) void att_k(const int* __restrict__ offs,
                                             const float* __restrict__ dS,
                                             const float* __restrict__ logit,
                                             float* __restrict__ att){
  int lane = threadIdx.x & 63;
  int node = (blockIdx.x * 256 + threadIdx.x) >> 6;
  if (node >= NN) return;
  int s0 = offs[node];
  int cnt = offs[node+1] - s0;
  if (cnt <= 0) return;
  const float NEG = -1e30f;
  if (cnt <= 64){
    bool act = lane < cnt;
    int p = s0 + (act ? lane : 0);
    float dd = dS[p];
    float4 lg = *reinterpret_cast<const float4*>(logit + 4*(size_t)p);
    float me  = wred_max(act ? -dd  : NEG);
    float ms0 = wred_max(act ? lg.x : NEG);
    float ms1 = wred_max(act ? lg.y : NEG);
    float ms2 = wred_max(act ? lg.z : NEG);
    float ms3 = wred_max(act ? lg.w : NEG);
    float ee  = act ? __expf(-dd - me)  : 0.f;
    float v0  = act ? __expf(lg.x - ms0) : 0.f;
    float v1  = act ? __expf(lg.y - ms1) : 0.f;
    float v2  = act ? __expf(lg.z - ms2) : 0.f;
    float v3  = act ? __expf(lg.w - ms3) : 0.f;
    float ise = 1.f / wred_sum(ee);
    float is0 = 1.f / wred_sum(v0);
    float is1 = 1.f / wred_sum(v1);
    float is2 = 1.f / wred_sum(v2);
    float is3 = 1.f / wred_sum(v3);
    float ae = ee * ise;
    float a0 = ae * v0 * is0, a1 = ae * v1 * is1;
    float a2 = ae * v2 * is2, a3 = ae * v3 * is3;
    float iz0 = 1.f / wred_sum(a0), iz1 = 1.f / wred_sum(a1);
    float iz2 = 1.f / wred_sum(a2), iz3 = 1.f / wred_sum(a3);
    if (act){
      float4 o; o.x = a0*iz0; o.y = a1*iz1; o.z = a2*iz2; o.w = a3*iz3;
      *reinterpret_cast<float4*>(att + 4*(size_t)p) = o;
    }
    return;
  }
  float me = NEG, ms0 = NEG, ms1 = NEG, ms2 = NEG, ms3 = NEG;
  for (int j = lane; j < cnt; j += 64){
    int p = s0 + j;
    float dd = dS[p];
    me = fmaxf(me, -dd);
    float4 lg = *reinterpret_cast<const float4*>(logit + 4*(size_t)p);
    ms0 = fmaxf(ms0, lg.x); ms1 = fmaxf(ms1, lg.y);
    ms2 = fmaxf(ms2, lg.z); ms3 = fmaxf(ms3, lg.w);
  }
  me = wred_max(me); ms0 = wred_max(ms0); ms1 = wred_max(ms1);
  ms2 = wred_max(ms2); ms3 = wred_max(ms3);
  float se = 0.f, ss0 = 0.f, ss1 = 0.f, ss2 = 0.f, ss3 = 0.f;
  for (int j = lane; j < cnt; j += 64){
    int p = s0 + j;
    float dd = dS[p];
    float4 lg = *reinterpret_cast<const float4*>(logit + 4*(size_t)p);
    se  += __expf(-dd - me);
    ss0 += __expf(lg.x - ms0); ss1 += __expf(lg.y - ms1);
    ss2 += __expf(lg.z - ms2); ss3 += __expf(lg.w - ms3);
  }
  se = wred_sum(se); ss0 = wred_sum(ss0); ss1 = wred_sum(ss1);
  ss2 = wred_sum(ss2); ss3 = wred_sum(ss3);
  float ise = 1.f/se, is0 = 1.f/ss0, is1 = 1.f/ss1, is2 = 1.f/ss2, is3 = 1.f/ss3;
  float z0 = 0.f, z1 = 0.f, z2 = 0.f, z3 = 0.f;
  for (int j = lane; j < cnt; j += 64){
    int p = s0 + j;
    float dd = dS[p];
    float4 lg = *reinterpret_cast<const float4*>(logit + 4*(size_t)p);
    float ae = __expf(-dd - me) * ise;
    z0 += ae * __expf(lg.x - ms0) * is0;
    z1 += ae * __expf(lg.y - ms1) * is1;
    z2 += ae * __expf(lg.z - ms2) * is2;
    z3 += ae * __expf(lg.w - ms3) * is3;
  }
  z0 = wred_sum(z0); z1 = wred_sum(z1); z2 = wred_sum(z2); z3 = wred_sum(z3);
  float iz0 = 1.f/z0, iz1 = 1.f/z1, iz2 = 1.f/z2, iz3 = 1.f/z3;
  for (int j = lane; j < cnt; j += 64){
    int p = s0 + j;
    float dd = dS[p];
    float4 lg = *reinterpret_cast<const float4*>(logit + 4*(size_t)p);
    float ae = __expf(-dd - me) * ise;
    float4 o;
    o.x = ae * __expf(lg.x - ms0) * is0 * iz0;
    o.y = ae * __expf(lg.y - ms1) * is1 * iz1;
    o.z = ae * __expf(lg.z - ms2) * is2 * iz2;
    o.w = ae * __expf(lg.w - ms3) * is3 * iz3;
    *reinterpret_cast<float4*>(att + 4*(size_t)p) = o;
  }
}

// ---- per-node aggregate (contiguous CSR) ----
__global__ __launch_bounds__(256) void agg_k(const int* __restrict__ offs,
                                             const u16* __restrict__ coef,
                                             const u16* __restrict__ he,
                                             const float* __restrict__ att,
                                             const float* __restrict__ dirsS,
                                             u16* __restrict__ cnorm,
                                             u16* __restrict__ node_in){
  int node = blockIdx.x;
  int c = threadIdx.x;
  int s0 = offs[node], s1 = offs[node+1];
  int q = c >> 2, hd = c & 3;
  float cs0 = 0.f, cs1 = 0.f, cs2 = 0.f, ha = 0.f;
  for (int p = s0; p < s1; ++p){
    float co = bf2f(coef[(size_t)p*256 + c]);
    float hv = bf2f(he[(size_t)p*64 + q]);
    float av = att[(size_t)p*4 + hd];
    float d0 = dirsS[3*(size_t)p], d1 = dirsS[3*(size_t)p+1], d2 = dirsS[3*(size_t)p+2];
    cs0 = fmaf(co, d0, cs0); cs1 = fmaf(co, d1, cs1); cs2 = fmaf(co, d2, cs2);
    ha = fmaf(hv, av, ha);
  }
  cnorm[(size_t)node*256 + c] = f2bf(cs0*cs0 + cs1*cs1 + cs2*cs2);
  node_in[(size_t)node*384 + 64 + c] = f2bf(ha);
}

// ---- graph pooling ----
__global__ __launch_bounds__(256) void segy_k(const float* __restrict__ hf,
                                              const int* __restrict__ seg,
                                              float* __restrict__ y){
  int gid = blockIdx.x * 256 + threadIdx.x;
  if (gid >= NN*64) return;
  int n = gid >> 6, ch = gid & 63;
  atomicAdd(&y[seg[n]*64 + ch], hf[gid]);
}

// ---- final head ----
__global__ void headf_k(const float* __restrict__ t2,
                        const float* __restrict__ w2,
                        const float* __restrict__ b2,
                        float* __restrict__ out){
  int s = threadIdx.x;
  if (s >= NSEG) return;
  float acc = b2[0];
  for (int k = 0; k < 64; ++k) acc = fmaf(t2[s*64 + k], w2[k], acc);
  out[s] = acc;
}

extern "C" void kernel_launch(void* const* d_in, const int* in_sizes, int n_in,
                              void* d_out, int out_size, void* d_ws, size_t ws_size,
                              hipStream_t stream) {
  (void)in_sizes; (void)n_in; (void)out_size; (void)ws_size;
  const float* in_i       = (const float*)d_in[0];
  const float* in_x       = (const float*)d_in[1];
  const float* emb_in_w   = (const float*)d_in[2];
  const float* emb_in_b   = (const float*)d_in[3];
  const float* edge_in_w  = (const float*)d_in[4];
  const float* edge_in_b  = (const float*)d_in[5];
  const float* rbf_means  = (const float*)d_in[6];
  const float* rbf_betas  = (const float*)d_in[7];
  const float* edge_o_w1  = (const float*)d_in[8];
  const float* edge_o_b1  = (const float*)d_in[9];
  const float* edge_o_w2  = (const float*)d_in[10];
  const float* edge_o_b2  = (const float*)d_in[11];
  const float* sem_w      = (const float*)d_in[12];
  const float* sem_b      = (const float*)d_in[13];
  const float* xmix_w     = (const float*)d_in[14];
  const float* pn_w1      = (const float*)d_in[15];
  const float* pn_b1      = (const float*)d_in[16];
  const float* pn_w2      = (const float*)d_in[17];
  const float* pn_b2      = (const float*)d_in[18];
  const float* node_w1    = (const float*)d_in[19];
  const float* node_b1    = (const float*)d_in[20];
  const float* node_w2    = (const float*)d_in[21];
  const float* node_b2    = (const float*)d_in[22];
  const float* emb_o_w1   = (const float*)d_in[23];
  const float* emb_o_b1   = (const float*)d_in[24];
  const float* emb_o_w2   = (const float*)d_in[25];
  const float* emb_o_b2   = (const float*)d_in[26];
  const float* head_w1    = (const float*)d_in[27];
  const float* head_b1    = (const float*)d_in[28];
  const float* head_w2    = (const float*)d_in[29];
  const float* head_b2    = (const float*)d_in[30];
  const int*   edges      = (const int*)d_in[31];
  const int*   segs       = (const int*)d_in[32];
  float* out = (float*)d_out;

  // workspace carve-up (256B aligned)
  char* base = (char*)d_ws;
  size_t off = 0;
  auto alloc = [&](size_t bytes) -> void* {
    void* p = base + off;
    off += (bytes + 255) & ~(size_t)255;
    return p;
  };
  float* dS     = (float*)alloc((size_t)EN*4);
  float* dirsS  = (float*)alloc((size_t)EN*3*4);
  float* rbfS   = (float*)alloc((size_t)EN*4);
  int*   edge_s = (int*)alloc((size_t)EN*2*4);
  float* hA     = (float*)alloc((size_t)NN*64*4);
  float* hB     = (float*)alloc((size_t)NN*64*4);
  u16*   he     = (u16*)alloc((size_t)EN*64*2);
  u16*   coef   = (u16*)alloc((size_t)EN*256*2);
  float* logit  = (float*)alloc((size_t)EN*4*4);
  float* att    = (float*)alloc((size_t)EN*4*4);
  u16*   hbf    = (u16*)alloc((size_t)NN*64*2);
  u16*   node_in= (u16*)alloc((size_t)NN*384*2);
  u16*   cnorm  = (u16*)alloc((size_t)NN*256*2);
  float* y      = (float*)alloc((size_t)NSEG*64*4);
  float* t2     = (float*)alloc((size_t)NSEG*64*4);
  u16* winb  = (u16*)alloc((size_t)DEPTH*64*128*2);
  u16* w1b   = (u16*)alloc((size_t)DEPTH*64*192*2);
  u16* w2b   = (u16*)alloc((size_t)DEPTH*64*64*2);
  u16* xwb   = (u16*)alloc((size_t)DEPTH*256*256*2);
  u16* pw1b  = (u16*)alloc((size_t)DEPTH*64*256*2);
  u16* pw2b  = (u16*)alloc((size_t)DEPTH*64*64*2);
  u16* nw1b  = (u16*)alloc((size_t)DEPTH*64*384*2);
  u16* nw2b  = (u16*)alloc((size_t)DEPTH*64*64*2);
  int* counts   = (int*)alloc((size_t)NN*4);
  int* cursor   = (int*)alloc((size_t)NN*4);
  int* offs     = (int*)alloc((size_t)(NN+1)*4);
  // fp32 scratch for final head, aliased over coef (dead by then)
  float* t_node = (float*)coef;

  hipMemsetAsync(counts, 0, (size_t)NN*4, stream);
  hipMemsetAsync(cursor, 0, (size_t)NN*4, stream);
  hipMemsetAsync(y, 0, (size_t)NSEG*64*4, stream);

  count_k<<<(EN+255)/256, 256, 0, stream>>>(edges, counts);
  scan_k<<<1, 256, 0, stream>>>(counts, offs);
  geoscat_k<<<(EN+255)/256, 256, 0, stream>>>(edges, in_x, offs, cursor,
                                              edge_s, dS, dirsS, rbfS);

  // weight conversions (once per call)
  convw_k<<<dim3(32,  DEPTH), 256, 0, stream>>>(edge_in_w, 128, 50, (size_t)128*50, winb, 128, 64, (size_t)64*128);
  convw_k<<<dim3(48,  DEPTH), 256, 0, stream>>>(edge_o_w1, 179, 64, (size_t)179*64, w1b,  192, 64, (size_t)64*192);
  convw_k<<<dim3(16,  DEPTH), 256, 0, stream>>>(edge_o_w2,  64, 64, (size_t)64*64,  w2b,   64, 64, (size_t)64*64);
  convw_k<<<dim3(256, DEPTH), 256, 0, stream>>>(xmix_w,    256,256, (size_t)256*256,xwb,  256,256, (size_t)256*256);
  convw_k<<<dim3(64,  DEPTH), 256, 0, stream>>>(pn_w1,     256, 64, (size_t)256*64, pw1b, 256, 64, (size_t)64*256);
  convw_k<<<dim3(16,  DEPTH), 256, 0, stream>>>(pn_w2,      64, 64, (size_t)64*64,  pw2b,  64, 64, (size_t)64*64);
  convw_k<<<dim3(96,  DEPTH), 256, 0, stream>>>(node_w1,   384, 64, (size_t)384*64, nw1b, 384, 64, (size_t)64*384);
  convw_k<<<dim3(16,  DEPTH), 256, 0, stream>>>(node_w2,    64, 64, (size_t)64*64,  nw2b,  64, 64, (size_t)64*64);

  // h = i @ emb_in_w + b   (fp32, K=16)
  gemm_k<0><<<dim3((NN+15)/16, 1), 256, 0, stream>>>(
      in_i, 16, emb_in_w, 64, emb_in_b, hA, 64, 0, NN, 64, 16);
  h2b_k<<<(NN*64)/256, 256, 0, stream>>>(hA, hbf, node_in);

  const int EB  = (EN + 63) / 64;     // 1563 edge tiles
  const int EB2 = (EN + 127) / 128;   // 782
  const int NB2 = (NN + 127) / 128;   // 79

  float* hcur = hA;
  float* hnext = hB;
  for (int l = 0; l < DEPTH; ++l){
    const float* bin  = edge_in_b + (size_t)l*50;
    const float* mean = rbf_means + (size_t)l*50;
    const float* beta = rbf_betas + (size_t)l*50;
    const float* b1   = edge_o_b1 + (size_t)l*64;
    const float* b2   = edge_o_b2 + (size_t)l*64;
    const float* sw   = sem_w + (size_t)l*64*4;
    const float* sb   = sem_b + (size_t)l*4;
    const float* pb1  = pn_b1 + (size_t)l*64;
    const float* pb2  = pn_b2 + (size_t)l*64;
    const float* nb1  = node_b1 + (size_t)l*64;
    const float* nb2  = node_b2 + (size_t)l*64;
    const u16* Winb = winb + (size_t)l*64*128;
    const u16* W1b  = w1b  + (size_t)l*64*192;
    const u16* W2b  = w2b  + (size_t)l*64*64;
    const u16* Xwb  = xwb  + (size_t)l*256*256;
    const u16* P1b  = pw1b + (size_t)l*64*256;
    const u16* P2b  = pw2b + (size_t)l*64*64;
    const u16* N1b  = nw1b + (size_t)l*64*384;
    const u16* N2b  = nw2b + (size_t)l*64*64;

    edge_fused_k<<<EB, 256, 0, stream>>>(edge_s, hbf, rbfS, dS,
                                         Winb, bin, mean, beta,
                                         W1b, b1, W2b, b2, sw, sb,
                                         he, logit);
    att_k<<<(NN+3)/4, 256, 0, stream>>>(offs, dS, logit, att);
    // coef = tanh((he x att) @ xmix)
    bgemm_k<2,8,1><<<dim3(EB2,2), 256, 0, stream>>>(
        he, 64, Xwb, 256, nullptr, nullptr, coef, 256, 0, EN, 256, 256, att);
    agg_k<<<NN, 256, 0, stream>>>(offs, coef, he, att, dirsS, cnorm, node_in);
    // h_comb -> node_in[:,320:384]
    mlp2_k<0><<<NB2, 256, 0, stream>>>(cnorm, 256, 256, P1b, pb1, P2b, pb2, NN,
                                       node_in, nullptr, nullptr, nullptr);
    // node update -> hnext, hbf, node_in[:,0:64]
    mlp2_k<1><<<NB2, 256, 0, stream>>>(node_in, 384, 384, N1b, nb1, N2b, nb2, NN,
                                       node_in, hcur, hnext, hbf);
    float* tmp = hcur; hcur = hnext; hnext = tmp;
  }

  // output head (fp32; t_node aliases coef which is dead now)
  gemm_k<1><<<dim3((NN+15)/16, 1), 256, 0, stream>>>(
      hcur, 64, emb_o_w1, 64, emb_o_b1, t_node, 64, 0, NN, 64, 64);
  gemm_k<0><<<dim3((NN+15)/16, 1), 256, 0, stream>>>(
      t_node, 64, emb_o_w2, 64, emb_o_b2, hnext, 64, 0, NN, 64, 64);
  segy_k<<<(NN*64)/256, 256, 0, stream>>>(hnext, segs, y);
  gemm_k<1><<<dim3((NSEG+15)/16, 1), 256, 0, stream>>>(
      y, 64, head_w1, 64, head_b1, t2, 64, 0, NSEG, 64, 64);
  headf_k<<<1, 128, 0, stream>>>(t2, head_w2, head_b2, out);
}